// Round 1
// baseline (3973.856 us; speedup 1.0000x reference)
//
#include <hip/hip_runtime.h>
#include <math.h>

#define B_ 16
#define S_ 256
#define T_ 2048
#define D_ 512
#define H_ 8
#define L_ 6
#define FF_ 2048
#define NM_ 80
#define M_ 4096  // B_*S_

// ---------------------------------------------------------------------------
// Embedding + positional encoding: x[r,:] = emb[ids[r],:] + pe[r%S,:]
// ---------------------------------------------------------------------------
__global__ __launch_bounds__(128) void embed_kernel(
    const int* __restrict__ ids, const float* __restrict__ emb,
    const float* __restrict__ pe, float* __restrict__ x)
{
    int r = blockIdx.x;
    int c = threadIdx.x * 4;
    int id = ids[r];
    int s = r & (S_ - 1);
    float4 e = *(const float4*)(emb + (size_t)id * D_ + c);
    float4 p = *(const float4*)(pe + (size_t)s * D_ + c);
    float4 o;
    o.x = e.x + p.x; o.y = e.y + p.y; o.z = e.z + p.z; o.w = e.w + p.w;
    *(float4*)(x + (size_t)r * D_ + c) = o;
}

// ---------------------------------------------------------------------------
// Generic fp32 GEMM: C[M,N] = act(A[M,K] @ Bw[K,N] + bias[N])
// M multiple of 128, N multiple of 128, K multiple of 16. act: 0 none, 1 relu
// 128x128 tile, 8x8 micro-tile, BK=16, 256 threads.
// ---------------------------------------------------------------------------
__global__ __launch_bounds__(256, 2) void gemm_f32(
    const float* __restrict__ A, const float* __restrict__ Bw,
    const float* __restrict__ bias, float* __restrict__ C,
    int N, int K, int act)
{
    __shared__ float As[16][132];
    __shared__ float Bs[16][132];
    const int tid = threadIdx.x;
    const int tx = tid & 15;   // col group (8 cols)
    const int ty = tid >> 4;   // row group (8 rows)
    const int m0 = blockIdx.y * 128;
    const int n0 = blockIdx.x * 128;

    float acc[8][8];
#pragma unroll
    for (int i = 0; i < 8; i++)
#pragma unroll
        for (int j = 0; j < 8; j++) acc[i][j] = 0.f;

    const int arow = tid >> 2;   // 0..63
    const int ac4  = tid & 3;    // 0..3
    const int brow = tid >> 5;   // 0..7
    const int bc4  = tid & 31;   // 0..31

    for (int kt = 0; kt < K; kt += 16) {
#pragma unroll
        for (int rr = 0; rr < 2; rr++) {
            int row = arow + rr * 64;
            float4 a = *(const float4*)(A + (size_t)(m0 + row) * K + kt + ac4 * 4);
            As[ac4 * 4 + 0][row] = a.x;
            As[ac4 * 4 + 1][row] = a.y;
            As[ac4 * 4 + 2][row] = a.z;
            As[ac4 * 4 + 3][row] = a.w;
        }
#pragma unroll
        for (int rr = 0; rr < 2; rr++) {
            int row = brow + rr * 8;
            float4 bv = *(const float4*)(Bw + (size_t)(kt + row) * N + n0 + bc4 * 4);
            *(float4*)&Bs[row][bc4 * 4] = bv;
        }
        __syncthreads();
#pragma unroll
        for (int kk = 0; kk < 16; kk++) {
            float4 a0 = *(const float4*)&As[kk][ty * 8];
            float4 a1 = *(const float4*)&As[kk][ty * 8 + 4];
            float4 b0 = *(const float4*)&Bs[kk][tx * 8];
            float4 b1 = *(const float4*)&Bs[kk][tx * 8 + 4];
            float av[8] = {a0.x, a0.y, a0.z, a0.w, a1.x, a1.y, a1.z, a1.w};
            float bv[8] = {b0.x, b0.y, b0.z, b0.w, b1.x, b1.y, b1.z, b1.w};
#pragma unroll
            for (int i = 0; i < 8; i++)
#pragma unroll
                for (int j = 0; j < 8; j++)
                    acc[i][j] = fmaf(av[i], bv[j], acc[i][j]);
        }
        __syncthreads();
    }

#pragma unroll
    for (int i = 0; i < 8; i++) {
        int row = m0 + ty * 8 + i;
#pragma unroll
        for (int j = 0; j < 8; j += 4) {
            int col = n0 + tx * 8 + j;
            float4 v;
            v.x = acc[i][j + 0] + bias[col + 0];
            v.y = acc[i][j + 1] + bias[col + 1];
            v.z = acc[i][j + 2] + bias[col + 2];
            v.w = acc[i][j + 3] + bias[col + 3];
            if (act) {
                v.x = fmaxf(v.x, 0.f); v.y = fmaxf(v.y, 0.f);
                v.z = fmaxf(v.z, 0.f); v.w = fmaxf(v.w, 0.f);
            }
            *(float4*)(C + (size_t)row * N + col) = v;
        }
    }
}

// ---------------------------------------------------------------------------
// Attention scores: scores[bh,m,n] = scale * sum_d q[m,d]*k[n,d] + mask(n)
// q rows at qkv[(b*S+m)*1536 + h*64], k at +512.  64x64 tile, 4x4 micro.
// ---------------------------------------------------------------------------
__global__ __launch_bounds__(256) void attn_scores(
    const float* __restrict__ qkv, const int* __restrict__ lens,
    float* __restrict__ scores)
{
    __shared__ float Qs[16][68];
    __shared__ float Ks[16][68];
    const int tid = threadIdx.x;
    const int tx = tid & 15, ty = tid >> 4;
    const int bh = blockIdx.z;
    const int b = bh >> 3, h = bh & 7;
    const int m0 = blockIdx.y * 64, n0 = blockIdx.x * 64;
    const int len = lens[b];
    const float* Qb = qkv + (size_t)b * S_ * 1536 + h * 64;
    const float* Kb = Qb + 512;

    float acc[4][4];
#pragma unroll
    for (int i = 0; i < 4; i++)
#pragma unroll
        for (int j = 0; j < 4; j++) acc[i][j] = 0.f;

    const int srow = tid >> 2, sc4 = tid & 3;
    for (int kt = 0; kt < 64; kt += 16) {
        float4 qv = *(const float4*)(Qb + (size_t)(m0 + srow) * 1536 + kt + sc4 * 4);
        float4 kv = *(const float4*)(Kb + (size_t)(n0 + srow) * 1536 + kt + sc4 * 4);
        Qs[sc4 * 4 + 0][srow] = qv.x; Qs[sc4 * 4 + 1][srow] = qv.y;
        Qs[sc4 * 4 + 2][srow] = qv.z; Qs[sc4 * 4 + 3][srow] = qv.w;
        Ks[sc4 * 4 + 0][srow] = kv.x; Ks[sc4 * 4 + 1][srow] = kv.y;
        Ks[sc4 * 4 + 2][srow] = kv.z; Ks[sc4 * 4 + 3][srow] = kv.w;
        __syncthreads();
#pragma unroll
        for (int kk = 0; kk < 16; kk++) {
            float4 a = *(const float4*)&Qs[kk][ty * 4];
            float4 bv = *(const float4*)&Ks[kk][tx * 4];
            float av[4] = {a.x, a.y, a.z, a.w};
            float bb[4] = {bv.x, bv.y, bv.z, bv.w};
#pragma unroll
            for (int i = 0; i < 4; i++)
#pragma unroll
                for (int j = 0; j < 4; j++)
                    acc[i][j] = fmaf(av[i], bb[j], acc[i][j]);
        }
        __syncthreads();
    }

    const float scale = 0.125f;  // 1/sqrt(64)
#pragma unroll
    for (int i = 0; i < 4; i++) {
        int m = m0 + ty * 4 + i;
        int col = n0 + tx * 4;
        float4 v;
        v.x = acc[i][0] * scale + ((col + 0 >= len) ? -1e9f : 0.f);
        v.y = acc[i][1] * scale + ((col + 1 >= len) ? -1e9f : 0.f);
        v.z = acc[i][2] * scale + ((col + 2 >= len) ? -1e9f : 0.f);
        v.w = acc[i][3] * scale + ((col + 3 >= len) ? -1e9f : 0.f);
        *(float4*)(scores + ((size_t)bh * S_ + m) * S_ + col) = v;
    }
}

// ---------------------------------------------------------------------------
// Row softmax over 256 cols; one wave per row, 4 rows per block.
// ---------------------------------------------------------------------------
__global__ __launch_bounds__(256) void softmax256(float* __restrict__ scores)
{
    const int tid = threadIdx.x;
    const int w = tid >> 6, lane = tid & 63;
    const size_t row = (size_t)blockIdx.x * 4 + w;
    float4* p = (float4*)(scores + row * S_);
    float4 v = p[lane];
    float m = fmaxf(fmaxf(v.x, v.y), fmaxf(v.z, v.w));
#pragma unroll
    for (int off = 32; off >= 1; off >>= 1) m = fmaxf(m, __shfl_xor(m, off, 64));
    float4 e;
    e.x = expf(v.x - m); e.y = expf(v.y - m);
    e.z = expf(v.z - m); e.w = expf(v.w - m);
    float s = e.x + e.y + e.z + e.w;
#pragma unroll
    for (int off = 32; off >= 1; off >>= 1) s += __shfl_xor(s, off, 64);
    float inv = 1.f / s;
    e.x *= inv; e.y *= inv; e.z *= inv; e.w *= inv;
    p[lane] = e;
}

// ---------------------------------------------------------------------------
// AV: o[(b*S+m)*512 + h*64 + n] = sum_k P[bh,m,k] * V[k,n]
// V rows at qkv[(b*S+k)*1536 + 1024 + h*64].  64 rows x 64 cols per block.
// ---------------------------------------------------------------------------
__global__ __launch_bounds__(256) void attn_av(
    const float* __restrict__ scores, const float* __restrict__ qkv,
    float* __restrict__ o)
{
    __shared__ float Ps[16][68];
    __shared__ float Vs[16][68];
    const int tid = threadIdx.x;
    const int tx = tid & 15, ty = tid >> 4;
    const int bh = blockIdx.z;
    const int b = bh >> 3, h = bh & 7;
    const int m0 = blockIdx.y * 64;
    const float* Pb = scores + (size_t)bh * S_ * S_;
    const float* Vb = qkv + (size_t)b * S_ * 1536 + 1024 + h * 64;

    float acc[4][4];
#pragma unroll
    for (int i = 0; i < 4; i++)
#pragma unroll
        for (int j = 0; j < 4; j++) acc[i][j] = 0.f;

    const int prow = tid >> 2, pc4 = tid & 3;   // 64 rows x 4 f4
    const int vrow = tid >> 4, vc4 = tid & 15;  // 16 rows x 16 f4
    for (int kt = 0; kt < S_; kt += 16) {
        float4 pv = *(const float4*)(Pb + (size_t)(m0 + prow) * S_ + kt + pc4 * 4);
        Ps[pc4 * 4 + 0][prow] = pv.x; Ps[pc4 * 4 + 1][prow] = pv.y;
        Ps[pc4 * 4 + 2][prow] = pv.z; Ps[pc4 * 4 + 3][prow] = pv.w;
        float4 vv = *(const float4*)(Vb + (size_t)(kt + vrow) * 1536 + vc4 * 4);
        *(float4*)&Vs[vrow][vc4 * 4] = vv;
        __syncthreads();
#pragma unroll
        for (int kk = 0; kk < 16; kk++) {
            float4 a = *(const float4*)&Ps[kk][ty * 4];
            float4 bv = *(const float4*)&Vs[kk][tx * 4];
            float av[4] = {a.x, a.y, a.z, a.w};
            float bb[4] = {bv.x, bv.y, bv.z, bv.w};
#pragma unroll
            for (int i = 0; i < 4; i++)
#pragma unroll
                for (int j = 0; j < 4; j++)
                    acc[i][j] = fmaf(av[i], bb[j], acc[i][j]);
        }
        __syncthreads();
    }

#pragma unroll
    for (int i = 0; i < 4; i++) {
        int m = m0 + ty * 4 + i;
        float4 v; v.x = acc[i][0]; v.y = acc[i][1]; v.z = acc[i][2]; v.w = acc[i][3];
        *(float4*)(o + (size_t)(b * S_ + m) * D_ + h * 64 + tx * 4) = v;
    }
}

// ---------------------------------------------------------------------------
// x = LayerNorm(x + y) * s + b ; one row (512) per block of 128 threads.
// ---------------------------------------------------------------------------
__global__ __launch_bounds__(128) void add_ln(
    float* __restrict__ x, const float* __restrict__ y,
    const float* __restrict__ s, const float* __restrict__ bb)
{
    __shared__ float red[2];
    const int row = blockIdx.x;
    const int tid = threadIdx.x;
    const int c = tid * 4;
    float4 xv = *(const float4*)(x + (size_t)row * D_ + c);
    float4 yv = *(const float4*)(y + (size_t)row * D_ + c);
    float4 h;
    h.x = xv.x + yv.x; h.y = xv.y + yv.y; h.z = xv.z + yv.z; h.w = xv.w + yv.w;

    float sum = h.x + h.y + h.z + h.w;
#pragma unroll
    for (int off = 32; off >= 1; off >>= 1) sum += __shfl_xor(sum, off, 64);
    if ((tid & 63) == 0) red[tid >> 6] = sum;
    __syncthreads();
    float mean = (red[0] + red[1]) * (1.f / 512.f);
    __syncthreads();

    float4 d;
    d.x = h.x - mean; d.y = h.y - mean; d.z = h.z - mean; d.w = h.w - mean;
    float sq = d.x * d.x + d.y * d.y + d.z * d.z + d.w * d.w;
#pragma unroll
    for (int off = 32; off >= 1; off >>= 1) sq += __shfl_xor(sq, off, 64);
    if ((tid & 63) == 0) red[tid >> 6] = sq;
    __syncthreads();
    float var = (red[0] + red[1]) * (1.f / 512.f);
    float rs = rsqrtf(var + 1e-5f);

    float4 sv = *(const float4*)(s + c);
    float4 bv = *(const float4*)(bb + c);
    float4 o;
    o.x = d.x * rs * sv.x + bv.x;
    o.y = d.y * rs * sv.y + bv.y;
    o.z = d.z * rs * sv.z + bv.z;
    o.w = d.w * rs * sv.w + bv.w;
    *(float4*)(x + (size_t)row * D_ + c) = o;
}

// ---------------------------------------------------------------------------
// Duration head stage 2: durations[r] = softplus(durh[r,:] . w2 + b2)
// One wave per row.
// ---------------------------------------------------------------------------
__global__ __launch_bounds__(256) void dur_head2(
    const float* __restrict__ durh, const float* __restrict__ w2,
    const float* __restrict__ b2, float* __restrict__ durout)
{
    const int tid = threadIdx.x;
    const int w = tid >> 6, lane = tid & 63;
    const int r = blockIdx.x * 4 + w;
    float4 h = *(const float4*)(durh + (size_t)r * 256 + lane * 4);
    float4 wv = *(const float4*)(w2 + lane * 4);
    float p = h.x * wv.x + h.y * wv.y + h.z * wv.z + h.w * wv.w;
#pragma unroll
    for (int off = 32; off >= 1; off >>= 1) p += __shfl_xor(p, off, 64);
    if (lane == 0) {
        float v = p + b2[0];
        durout[r] = (v > 20.f) ? v : log1pf(expf(v));
    }
}

// ---------------------------------------------------------------------------
// Per-batch inclusive cumsum of max(round(dur),1)
// ---------------------------------------------------------------------------
__global__ __launch_bounds__(256) void dur_cumsum(
    const float* __restrict__ dur, int* __restrict__ cum)
{
    __shared__ int sc[256];
    const int b = blockIdx.x, s = threadIdx.x;
    int d = (int)rintf(dur[b * 256 + s]);
    if (d < 1) d = 1;
    sc[s] = d;
    __syncthreads();
    for (int off = 1; off < 256; off <<= 1) {
        int v = sc[s];
        int add = (s >= off) ? sc[s - off] : 0;
        __syncthreads();
        sc[s] = v + add;
        __syncthreads();
    }
    cum[b * 256 + s] = sc[s];
}

// ---------------------------------------------------------------------------
// mel second GEMM: mel_s[r, c] = melh[r,:] @ W2[:,c] + b2[c]  (N=80, K=2048)
// 4 rows per block, 320 threads: c = tid%80, quarter q = tid/80.
// ---------------------------------------------------------------------------
__global__ __launch_bounds__(320) void mel_out_gemm(
    const float* __restrict__ melh, const float* __restrict__ W2,
    const float* __restrict__ b2, float* __restrict__ mel_s)
{
    __shared__ float hs[4 * 2048];
    __shared__ float red[16 * 80];
    const int tid = threadIdx.x;
    const int r0 = blockIdx.x * 4;
    for (int i = tid; i < 4 * 2048; i += 320)
        hs[i] = melh[(size_t)r0 * 2048 + i];
    __syncthreads();

    const int c = tid % 80;
    const int q = tid / 80;  // 0..3
    float acc[4] = {0.f, 0.f, 0.f, 0.f};
    for (int f = q * 512; f < q * 512 + 512; f++) {
        float wv = W2[(size_t)f * 80 + c];
#pragma unroll
        for (int r = 0; r < 4; r++) acc[r] = fmaf(hs[r * 2048 + f], wv, acc[r]);
    }
#pragma unroll
    for (int r = 0; r < 4; r++) red[(q * 4 + r) * 80 + c] = acc[r];
    __syncthreads();
    if (q == 0) {
#pragma unroll
        for (int r = 0; r < 4; r++) {
            float v = red[r * 80 + c] + red[(4 + r) * 80 + c] +
                      red[(8 + r) * 80 + c] + red[(12 + r) * 80 + c] + b2[c];
            mel_s[(size_t)(r0 + r) * 80 + c] = v;
        }
    }
}

// ---------------------------------------------------------------------------
// Constant mel row for invalid positions: c0[c] = relu(b1) @ W2 + b2
// ---------------------------------------------------------------------------
__global__ __launch_bounds__(256) void mel_c0(
    const float* __restrict__ b1, const float* __restrict__ W2,
    const float* __restrict__ b2, float* __restrict__ c0)
{
    __shared__ float red[4];
    const int c = blockIdx.x;
    const int tid = threadIdx.x;
    float p = 0.f;
    for (int f = tid; f < 2048; f += 256)
        p += fmaxf(b1[f], 0.f) * W2[(size_t)f * 80 + c];
#pragma unroll
    for (int off = 32; off >= 1; off >>= 1) p += __shfl_xor(p, off, 64);
    if ((tid & 63) == 0) red[tid >> 6] = p;
    __syncthreads();
    if (tid == 0) c0[c] = red[0] + red[1] + red[2] + red[3] + b2[c];
}

// ---------------------------------------------------------------------------
// Gather mel rows into [B, NM, T] output via duration index.
// ---------------------------------------------------------------------------
__global__ __launch_bounds__(256) void mel_gather(
    const float* __restrict__ mel_s, const float* __restrict__ c0,
    const int* __restrict__ cum, float* __restrict__ mel_out)
{
    __shared__ int sc[256];
    __shared__ float s0[80];
    const int b = blockIdx.y;
    const int t = blockIdx.x * 256 + threadIdx.x;
    sc[threadIdx.x] = cum[b * 256 + threadIdx.x];
    if (threadIdx.x < 80) s0[threadIdx.x] = c0[threadIdx.x];
    __syncthreads();
    const int total = sc[255];
    int lo = 0, hi = 256;
    while (lo < hi) {
        int mid = (lo + hi) >> 1;
        if (sc[mid] <= t) lo = mid + 1; else hi = mid;
    }
    int row = lo < 255 ? lo : 255;
    const bool valid = t < total;
    const float* src = mel_s + ((size_t)b * 256 + row) * 80;
    for (int cc = 0; cc < 80; cc++) {
        float v = valid ? src[cc] : s0[cc];
        mel_out[((size_t)b * 80 + cc) * T_ + t] = v;
    }
}

// ---------------------------------------------------------------------------
extern "C" void kernel_launch(void* const* d_in, const int* in_sizes, int n_in,
                              void* d_out, int out_size, void* d_ws, size_t ws_size,
                              hipStream_t stream)
{
    const int*   text_ids     = (const int*)d_in[0];
    const int*   text_lengths = (const int*)d_in[1];
    const float* emb   = (const float*)d_in[3];
    const float* pe    = (const float*)d_in[4];
    const float* Wqkv  = (const float*)d_in[5];
    const float* bqkv  = (const float*)d_in[6];
    const float* Wo    = (const float*)d_in[7];
    const float* bo    = (const float*)d_in[8];
    const float* ln1_s = (const float*)d_in[9];
    const float* ln1_b = (const float*)d_in[10];
    const float* ln2_s = (const float*)d_in[11];
    const float* ln2_b = (const float*)d_in[12];
    const float* W1    = (const float*)d_in[13];
    const float* b1    = (const float*)d_in[14];
    const float* W2    = (const float*)d_in[15];
    const float* b2    = (const float*)d_in[16];
    const float* mel_W1 = (const float*)d_in[17];
    const float* mel_b1 = (const float*)d_in[18];
    const float* mel_W2 = (const float*)d_in[19];
    const float* mel_b2 = (const float*)d_in[20];
    const float* dur_W1 = (const float*)d_in[21];
    const float* dur_b1 = (const float*)d_in[22];
    const float* dur_W2 = (const float*)d_in[23];
    const float* dur_b2 = (const float*)d_in[24];

    float* out = (float*)d_out;
    float* mel_out = out;                                   // B*NM*T = 2,621,440
    float* dur_out = out + (size_t)B_ * NM_ * T_;           // B*S    = 4,096
    float* enc_out = dur_out + (size_t)B_ * S_;             // B*S*D  = 2,097,152

    float* ws = (float*)d_ws;
    float* x      = ws;                                     // 2,097,152
    float* qkvb   = x + (size_t)M_ * D_;                    // 6,291,456
    float* attn_o = qkvb + (size_t)M_ * 3 * D_;             // 2,097,152
    float* yb     = attn_o + (size_t)M_ * D_;               // 2,097,152
    float* big    = yb + (size_t)M_ * D_;                   // 8,388,608 (scores / ffh / durh / melh)
    float* mel_s  = big + (size_t)8388608;                  // 327,680
    float* c0     = mel_s + (size_t)M_ * NM_;               // 80 (+pad)
    int*   cum    = (int*)(c0 + 128);                       // 4,096 ints

    embed_kernel<<<M_, 128, 0, stream>>>(text_ids, emb, pe, x);

    for (int l = 0; l < L_; l++) {
        gemm_f32<<<dim3(1536 / 128, M_ / 128), 256, 0, stream>>>(
            x, Wqkv + (size_t)l * D_ * 3 * D_, bqkv + (size_t)l * 3 * D_, qkvb, 1536, 512, 0);
        attn_scores<<<dim3(4, 4, 128), 256, 0, stream>>>(qkvb, text_lengths, big);
        softmax256<<<(B_ * H_ * S_) / 4, 256, 0, stream>>>(big);
        attn_av<<<dim3(1, 4, 128), 256, 0, stream>>>(big, qkvb, attn_o);
        gemm_f32<<<dim3(512 / 128, M_ / 128), 256, 0, stream>>>(
            attn_o, Wo + (size_t)l * D_ * D_, bo + (size_t)l * D_, yb, 512, 512, 0);
        add_ln<<<M_, 128, 0, stream>>>(x, yb, ln1_s + (size_t)l * D_, ln1_b + (size_t)l * D_);
        gemm_f32<<<dim3(2048 / 128, M_ / 128), 256, 0, stream>>>(
            x, W1 + (size_t)l * D_ * FF_, b1 + (size_t)l * FF_, big, 2048, 512, 1);
        gemm_f32<<<dim3(512 / 128, M_ / 128), 256, 0, stream>>>(
            big, W2 + (size_t)l * FF_ * D_, b2 + (size_t)l * D_, yb, 512, 2048, 0);
        add_ln<<<M_, 128, 0, stream>>>(x, yb, ln2_s + (size_t)l * D_, ln2_b + (size_t)l * D_);
    }

    // enc output (x holds final encoder state)
    hipMemcpyAsync(enc_out, x, (size_t)M_ * D_ * sizeof(float),
                   hipMemcpyDeviceToDevice, stream);

    // duration head
    gemm_f32<<<dim3(256 / 128, M_ / 128), 256, 0, stream>>>(
        x, dur_W1, dur_b1, big, 256, 512, 1);
    dur_head2<<<M_ / 4, 256, 0, stream>>>(big, dur_W2, dur_b2, dur_out);
    dur_cumsum<<<B_, 256, 0, stream>>>(dur_out, cum);

    // mel head on enc rows (B*S of them), then gather to [B,NM,T]
    gemm_f32<<<dim3(2048 / 128, M_ / 128), 256, 0, stream>>>(
        x, mel_W1, mel_b1, big, 2048, 512, 1);
    mel_out_gemm<<<M_ / 4, 320, 0, stream>>>(big, mel_W2, mel_b2, mel_s);
    mel_c0<<<NM_, 256, 0, stream>>>(mel_b1, mel_W2, mel_b2, c0);
    mel_gather<<<dim3(T_ / 256, B_), 256, 0, stream>>>(mel_s, c0, cum, mel_out);
}

// Round 2
// 1400.990 us; speedup vs baseline: 2.8365x; 2.8365x over previous
//
#include <hip/hip_runtime.h>
#include <math.h>

#define B_ 16
#define S_ 256
#define T_ 2048
#define D_ 512
#define H_ 8
#define L_ 6
#define FF_ 2048
#define NM_ 80
#define M_ 4096  // B_*S_

typedef float floatx4 __attribute__((ext_vector_type(4)));
typedef __bf16 bf16x8 __attribute__((ext_vector_type(8)));

__device__ __forceinline__ float bf2f(unsigned u) {
    return __uint_as_float((u & 0xffffu) << 16);
}
__device__ __forceinline__ unsigned short f2bf(float f) {
    unsigned u = __float_as_uint(f);
    unsigned r = u + 0x7fffu + ((u >> 16) & 1u);
    return (unsigned short)(r >> 16);
}
__device__ __forceinline__ void unpack8(uint4 rv, float* f) {
    f[0] = bf2f(rv.x); f[1] = bf2f(rv.x >> 16);
    f[2] = bf2f(rv.y); f[3] = bf2f(rv.y >> 16);
    f[4] = bf2f(rv.z); f[5] = bf2f(rv.z >> 16);
    f[6] = bf2f(rv.w); f[7] = bf2f(rv.w >> 16);
}
__device__ __forceinline__ void gload_lds16(const void* g, void* l) {
    __builtin_amdgcn_global_load_lds(
        (const __attribute__((address_space(1))) void*)g,
        (__attribute__((address_space(3))) void*)l, 16, 0, 0);
}

// ---------------------------------------------------------------------------
// Tiled transpose + f32->bf16: src [Z][K][N] -> dst [Z][N][K] (bf16)
// ---------------------------------------------------------------------------
__global__ __launch_bounds__(256) void transpose_bf16(
    const float* __restrict__ src, unsigned short* __restrict__ dst,
    int K, int N)
{
    __shared__ float tile[32][33];
    const int k0 = blockIdx.y * 32, n0 = blockIdx.x * 32;
    src += (size_t)blockIdx.z * K * N;
    dst += (size_t)blockIdx.z * K * N;
    const int tx = threadIdx.x, ty = threadIdx.y;
#pragma unroll
    for (int i = 0; i < 32; i += 8)
        tile[ty + i][tx] = src[(size_t)(k0 + ty + i) * N + n0 + tx];
    __syncthreads();
#pragma unroll
    for (int i = 0; i < 32; i += 8)
        dst[(size_t)(n0 + ty + i) * K + k0 + tx] = f2bf(tile[tx][ty + i]);
}

// ---------------------------------------------------------------------------
// Embedding + positional encoding -> bf16 x
// ---------------------------------------------------------------------------
__global__ __launch_bounds__(128) void embed_bf16(
    const int* __restrict__ ids, const float* __restrict__ emb,
    const float* __restrict__ pe, unsigned short* __restrict__ x)
{
    const int r = blockIdx.x;
    const int c = threadIdx.x * 4;
    const int id = ids[r];
    const int s = r & (S_ - 1);
    float4 e = *(const float4*)(emb + (size_t)id * D_ + c);
    float4 p = *(const float4*)(pe + (size_t)s * D_ + c);
    ushort4 o;
    o.x = f2bf(e.x + p.x); o.y = f2bf(e.y + p.y);
    o.z = f2bf(e.z + p.z); o.w = f2bf(e.w + p.w);
    *(ushort4*)(x + (size_t)r * D_ + c) = o;
}

// ---------------------------------------------------------------------------
// bf16 MFMA GEMM: C = act(A[M,K](bf16) @ Bt[N,K]^T(bf16) + bias[N](f32))
// 128x128 tile, BK=64, 4 waves, 16x16x32 MFMA, fragment-ordered LDS staging
// via global_load_lds(16B). M%128==0, N%128==0 or N==256, K%64==0.
// ---------------------------------------------------------------------------
__global__ __launch_bounds__(256) void gemm_bf16(
    const unsigned short* __restrict__ A, const unsigned short* __restrict__ Bt,
    const float* __restrict__ bias, float* __restrict__ Cf,
    unsigned short* __restrict__ Cb, int N, int K, int act, int wf, int wb)
{
    __shared__ __attribute__((aligned(16))) char smem[32768];
    char* sA = smem;
    char* sB = smem + 16384;

    const int tid = threadIdx.x;
    const int wave = tid >> 6, lane = tid & 63;
    const int lm = lane & 15, quad = lane >> 4;
    const int wm = wave >> 1, wn = wave & 1;
    const int m0 = blockIdx.y * 128;
    const int n0 = blockIdx.x * 128;

    floatx4 acc[4][4];
#pragma unroll
    for (int i = 0; i < 4; i++)
#pragma unroll
        for (int j = 0; j < 4; j++) acc[i][j] = (floatx4){0.f, 0.f, 0.f, 0.f};

    // per-wave staging streams: 8 subtiles (sid<16 -> A, else B)
    const unsigned short* ga[8];
    char* lds[8];
#pragma unroll
    for (int j = 0; j < 8; j++) {
        int sid = wave * 8 + j;
        if (sid < 16) {
            int mi = sid >> 1, ki = sid & 1;
            ga[j] = A + (size_t)(m0 + mi * 16 + lm) * K + ki * 32 + quad * 8;
            lds[j] = sA + sid * 1024;
        } else {
            int t = sid - 16;
            int ni = t >> 1, ki = t & 1;
            ga[j] = Bt + (size_t)(n0 + ni * 16 + lm) * K + ki * 32 + quad * 8;
            lds[j] = sB + t * 1024;
        }
    }

    for (int kt = 0; kt < K; kt += 64) {
        __syncthreads();
#pragma unroll
        for (int j = 0; j < 8; j++) gload_lds16(ga[j] + kt, lds[j]);
        __syncthreads();
#pragma unroll
        for (int ki = 0; ki < 2; ki++) {
            bf16x8 af[4], bf[4];
#pragma unroll
            for (int i = 0; i < 4; i++) {
                af[i] = *(const bf16x8*)(sA + ((((wm * 4 + i) * 2 + ki) << 10) + (lane << 4)));
                bf[i] = *(const bf16x8*)(sB + ((((wn * 4 + i) * 2 + ki) << 10) + (lane << 4)));
            }
#pragma unroll
            for (int i = 0; i < 4; i++)
#pragma unroll
                for (int j = 0; j < 4; j++)
                    acc[i][j] = __builtin_amdgcn_mfma_f32_16x16x32_bf16(
                        af[i], bf[j], acc[i][j], 0, 0, 0);
        }
    }

#pragma unroll
    for (int mi = 0; mi < 4; mi++) {
        const int rb = m0 + wm * 64 + mi * 16 + quad * 4;
#pragma unroll
        for (int ni = 0; ni < 4; ni++) {
            const int col = n0 + wn * 64 + ni * 16 + lm;
            const float bv = bias[col];
#pragma unroll
            for (int r = 0; r < 4; r++) {
                float o = acc[mi][ni][r] + bv;
                if (act) o = fmaxf(o, 0.f);
                if (wf) Cf[(size_t)(rb + r) * N + col] = o;
                if (wb) Cb[(size_t)(rb + r) * N + col] = f2bf(o);
            }
        }
    }
}

// ---------------------------------------------------------------------------
// Attention scores (fp32 FMA, bf16 I/O): 64x64 tile over (q,k), DH=64
// ---------------------------------------------------------------------------
__global__ __launch_bounds__(256) void attn_scores_bf16(
    const unsigned short* __restrict__ qkv, const int* __restrict__ lens,
    unsigned short* __restrict__ scores)
{
    __shared__ float Qs[16][68];
    __shared__ float Ks[16][68];
    const int tid = threadIdx.x;
    const int tx = tid & 15, ty = tid >> 4;
    const int bh = blockIdx.z;
    const int b = bh >> 3, h = bh & 7;
    const int m0 = blockIdx.y * 64, n0 = blockIdx.x * 64;
    const int len = lens[b];
    const unsigned short* Qb = qkv + (size_t)b * S_ * 1536 + h * 64;
    const unsigned short* Kb = Qb + 512;

    float acc[4][4];
#pragma unroll
    for (int i = 0; i < 4; i++)
#pragma unroll
        for (int j = 0; j < 4; j++) acc[i][j] = 0.f;

    const bool isK = tid >= 128;
    const int srow = (tid & 127) >> 1, half = tid & 1;
    const unsigned short* base = (isK ? Kb : Qb) + (size_t)((isK ? n0 : m0) + srow) * 1536;

    for (int kt = 0; kt < 64; kt += 16) {
        uint4 rv = *(const uint4*)(base + kt + half * 8);
        float f[8]; unpack8(rv, f);
        float (*Ts)[68] = isK ? Ks : Qs;
#pragma unroll
        for (int j = 0; j < 8; j++) Ts[half * 8 + j][srow] = f[j];
        __syncthreads();
#pragma unroll
        for (int kk = 0; kk < 16; kk++) {
            float4 a = *(const float4*)&Qs[kk][ty * 4];
            float4 bv = *(const float4*)&Ks[kk][tx * 4];
            float av[4] = {a.x, a.y, a.z, a.w};
            float bb[4] = {bv.x, bv.y, bv.z, bv.w};
#pragma unroll
            for (int i = 0; i < 4; i++)
#pragma unroll
                for (int j = 0; j < 4; j++)
                    acc[i][j] = fmaf(av[i], bb[j], acc[i][j]);
        }
        __syncthreads();
    }

    const float scale = 0.125f;
#pragma unroll
    for (int i = 0; i < 4; i++) {
        const int m = m0 + ty * 4 + i;
        const int col = n0 + tx * 4;
        ushort4 v;
        v.x = f2bf(acc[i][0] * scale + ((col + 0 >= len) ? -1e9f : 0.f));
        v.y = f2bf(acc[i][1] * scale + ((col + 1 >= len) ? -1e9f : 0.f));
        v.z = f2bf(acc[i][2] * scale + ((col + 2 >= len) ? -1e9f : 0.f));
        v.w = f2bf(acc[i][3] * scale + ((col + 3 >= len) ? -1e9f : 0.f));
        *(ushort4*)(scores + ((size_t)bh * S_ + m) * S_ + col) = v;
    }
}

// ---------------------------------------------------------------------------
// Row softmax over 256 bf16 cols; one wave per row, 4 rows/block.
// ---------------------------------------------------------------------------
__global__ __launch_bounds__(256) void softmax_bf16(unsigned short* __restrict__ scores)
{
    const int tid = threadIdx.x;
    const int w = tid >> 6, lane = tid & 63;
    const size_t row = (size_t)blockIdx.x * 4 + w;
    unsigned short* p = scores + row * S_ + lane * 4;
    uint2 rv = *(const uint2*)p;
    float v[4];
    v[0] = bf2f(rv.x); v[1] = bf2f(rv.x >> 16);
    v[2] = bf2f(rv.y); v[3] = bf2f(rv.y >> 16);
    float m = fmaxf(fmaxf(v[0], v[1]), fmaxf(v[2], v[3]));
#pragma unroll
    for (int off = 32; off >= 1; off >>= 1) m = fmaxf(m, __shfl_xor(m, off, 64));
    float e0 = expf(v[0] - m), e1 = expf(v[1] - m);
    float e2 = expf(v[2] - m), e3 = expf(v[3] - m);
    float s = e0 + e1 + e2 + e3;
#pragma unroll
    for (int off = 32; off >= 1; off >>= 1) s += __shfl_xor(s, off, 64);
    float inv = 1.f / s;
    uint2 ov;
    ov.x = (unsigned)f2bf(e0 * inv) | ((unsigned)f2bf(e1 * inv) << 16);
    ov.y = (unsigned)f2bf(e2 * inv) | ((unsigned)f2bf(e3 * inv) << 16);
    *(uint2*)p = ov;
}

// ---------------------------------------------------------------------------
// AV (fp32 FMA, bf16 I/O): 32(m) x 64(n) tile, K=256
// ---------------------------------------------------------------------------
__global__ __launch_bounds__(256) void attn_av_bf16(
    const unsigned short* __restrict__ scores, const unsigned short* __restrict__ qkv,
    unsigned short* __restrict__ o)
{
    __shared__ float Ps[16][36];
    __shared__ float Vs[16][68];
    const int tid = threadIdx.x;
    const int tx = tid & 15, ty = tid >> 4;
    const int bh = blockIdx.z;
    const int b = bh >> 3, h = bh & 7;
    const int m0 = blockIdx.y * 32;
    const unsigned short* Pb = scores + (size_t)bh * S_ * S_;
    const unsigned short* Vb = qkv + (size_t)b * S_ * 1536 + 1024 + h * 64;

    float acc[2][4];
#pragma unroll
    for (int i = 0; i < 2; i++)
#pragma unroll
        for (int j = 0; j < 4; j++) acc[i][j] = 0.f;

    const int prow = tid >> 1, phalf = tid & 1;      // tid<64
    const int vt = tid - 128, vrow = vt >> 3, vc8 = vt & 7;  // tid>=128

    for (int kt = 0; kt < S_; kt += 16) {
        if (tid < 64) {
            uint4 rv = *(const uint4*)(Pb + (size_t)(m0 + prow) * S_ + kt + phalf * 8);
            float f[8]; unpack8(rv, f);
#pragma unroll
            for (int j = 0; j < 8; j++) Ps[phalf * 8 + j][prow] = f[j];
        } else if (tid >= 128) {
            uint4 rv = *(const uint4*)(Vb + (size_t)(kt + vrow) * 1536 + vc8 * 8);
            float f[8]; unpack8(rv, f);
#pragma unroll
            for (int j = 0; j < 8; j++) Vs[vrow][vc8 * 8 + j] = f[j];
        }
        __syncthreads();
#pragma unroll
        for (int kk = 0; kk < 16; kk++) {
            float a0 = Ps[kk][ty * 2 + 0];
            float a1 = Ps[kk][ty * 2 + 1];
            float4 bv = *(const float4*)&Vs[kk][tx * 4];
            acc[0][0] = fmaf(a0, bv.x, acc[0][0]); acc[0][1] = fmaf(a0, bv.y, acc[0][1]);
            acc[0][2] = fmaf(a0, bv.z, acc[0][2]); acc[0][3] = fmaf(a0, bv.w, acc[0][3]);
            acc[1][0] = fmaf(a1, bv.x, acc[1][0]); acc[1][1] = fmaf(a1, bv.y, acc[1][1]);
            acc[1][2] = fmaf(a1, bv.z, acc[1][2]); acc[1][3] = fmaf(a1, bv.w, acc[1][3]);
        }
        __syncthreads();
    }

#pragma unroll
    for (int i = 0; i < 2; i++) {
        const int m = m0 + ty * 2 + i;
        ushort4 v;
        v.x = f2bf(acc[i][0]); v.y = f2bf(acc[i][1]);
        v.z = f2bf(acc[i][2]); v.w = f2bf(acc[i][3]);
        *(ushort4*)(o + (size_t)(b * S_ + m) * D_ + h * 64 + tx * 4) = v;
    }
}

// ---------------------------------------------------------------------------
// x = LayerNorm(x + y) (bf16 in/out, fp32 math); optional fp32 enc out.
// ---------------------------------------------------------------------------
__global__ __launch_bounds__(128) void add_ln_bf16(
    unsigned short* __restrict__ x, const unsigned short* __restrict__ y,
    const float* __restrict__ s, const float* __restrict__ bb,
    float* __restrict__ enc_opt)
{
    __shared__ float red[2];
    const int row = blockIdx.x;
    const int tid = threadIdx.x;
    const int c = tid * 4;
    ushort4 xv = *(const ushort4*)(x + (size_t)row * D_ + c);
    ushort4 yv = *(const ushort4*)(y + (size_t)row * D_ + c);
    float h[4];
    h[0] = bf2f(xv.x) + bf2f(yv.x);
    h[1] = bf2f(xv.y) + bf2f(yv.y);
    h[2] = bf2f(xv.z) + bf2f(yv.z);
    h[3] = bf2f(xv.w) + bf2f(yv.w);

    float sum = h[0] + h[1] + h[2] + h[3];
#pragma unroll
    for (int off = 32; off >= 1; off >>= 1) sum += __shfl_xor(sum, off, 64);
    if ((tid & 63) == 0) red[tid >> 6] = sum;
    __syncthreads();
    float mean = (red[0] + red[1]) * (1.f / 512.f);
    __syncthreads();

    float d[4];
    d[0] = h[0] - mean; d[1] = h[1] - mean; d[2] = h[2] - mean; d[3] = h[3] - mean;
    float sq = d[0] * d[0] + d[1] * d[1] + d[2] * d[2] + d[3] * d[3];
#pragma unroll
    for (int off = 32; off >= 1; off >>= 1) sq += __shfl_xor(sq, off, 64);
    if ((tid & 63) == 0) red[tid >> 6] = sq;
    __syncthreads();
    float var = (red[0] + red[1]) * (1.f / 512.f);
    float rs = rsqrtf(var + 1e-5f);

    float4 sv = *(const float4*)(s + c);
    float4 bv = *(const float4*)(bb + c);
    float o[4];
    o[0] = d[0] * rs * sv.x + bv.x;
    o[1] = d[1] * rs * sv.y + bv.y;
    o[2] = d[2] * rs * sv.z + bv.z;
    o[3] = d[3] * rs * sv.w + bv.w;
    ushort4 ov;
    ov.x = f2bf(o[0]); ov.y = f2bf(o[1]); ov.z = f2bf(o[2]); ov.w = f2bf(o[3]);
    *(ushort4*)(x + (size_t)row * D_ + c) = ov;
    if (enc_opt) {
        float4 e; e.x = o[0]; e.y = o[1]; e.z = o[2]; e.w = o[3];
        *(float4*)(enc_opt + (size_t)row * D_ + c) = e;
    }
}

// ---------------------------------------------------------------------------
// Duration head stage 2 (durh fp32)
// ---------------------------------------------------------------------------
__global__ __launch_bounds__(256) void dur_head2(
    const float* __restrict__ durh, const float* __restrict__ w2,
    const float* __restrict__ b2, float* __restrict__ durout)
{
    const int tid = threadIdx.x;
    const int w = tid >> 6, lane = tid & 63;
    const int r = blockIdx.x * 4 + w;
    float4 h = *(const float4*)(durh + (size_t)r * 256 + lane * 4);
    float4 wv = *(const float4*)(w2 + lane * 4);
    float p = h.x * wv.x + h.y * wv.y + h.z * wv.z + h.w * wv.w;
#pragma unroll
    for (int off = 32; off >= 1; off >>= 1) p += __shfl_xor(p, off, 64);
    if (lane == 0) {
        float v = p + b2[0];
        durout[r] = (v > 20.f) ? v : log1pf(expf(v));
    }
}

__global__ __launch_bounds__(256) void dur_cumsum(
    const float* __restrict__ dur, int* __restrict__ cum)
{
    __shared__ int sc[256];
    const int b = blockIdx.x, s = threadIdx.x;
    int d = (int)rintf(dur[b * 256 + s]);
    if (d < 1) d = 1;
    sc[s] = d;
    __syncthreads();
    for (int off = 1; off < 256; off <<= 1) {
        int v = sc[s];
        int add = (s >= off) ? sc[s - off] : 0;
        __syncthreads();
        sc[s] = v + add;
        __syncthreads();
    }
    cum[b * 256 + s] = sc[s];
}

// ---------------------------------------------------------------------------
// mel second GEMM (melh bf16): mel_s[r,c] = melh[r,:] @ W2[:,c] + b2[c]
// ---------------------------------------------------------------------------
__global__ __launch_bounds__(320) void mel_out_gemm(
    const unsigned short* __restrict__ melh, const float* __restrict__ W2,
    const float* __restrict__ b2, float* __restrict__ mel_s)
{
    __shared__ float hs[4 * 2048];
    __shared__ float red[16 * 80];
    const int tid = threadIdx.x;
    const int r0 = blockIdx.x * 4;
    for (int i = tid; i < 4 * 2048; i += 320)
        hs[i] = bf2f(melh[(size_t)r0 * 2048 + i]);
    __syncthreads();

    const int c = tid % 80;
    const int q = tid / 80;
    float acc[4] = {0.f, 0.f, 0.f, 0.f};
    for (int f = q * 512; f < q * 512 + 512; f++) {
        float wv = W2[(size_t)f * 80 + c];
#pragma unroll
        for (int r = 0; r < 4; r++) acc[r] = fmaf(hs[r * 2048 + f], wv, acc[r]);
    }
#pragma unroll
    for (int r = 0; r < 4; r++) red[(q * 4 + r) * 80 + c] = acc[r];
    __syncthreads();
    if (q == 0) {
#pragma unroll
        for (int r = 0; r < 4; r++) {
            float v = red[r * 80 + c] + red[(4 + r) * 80 + c] +
                      red[(8 + r) * 80 + c] + red[(12 + r) * 80 + c] + b2[c];
            mel_s[(size_t)(r0 + r) * 80 + c] = v;
        }
    }
}

__global__ __launch_bounds__(256) void mel_c0(
    const float* __restrict__ b1, const float* __restrict__ W2,
    const float* __restrict__ b2, float* __restrict__ c0)
{
    __shared__ float red[4];
    const int c = blockIdx.x;
    const int tid = threadIdx.x;
    float p = 0.f;
    for (int f = tid; f < 2048; f += 256)
        p += fmaxf(b1[f], 0.f) * W2[(size_t)f * 80 + c];
#pragma unroll
    for (int off = 32; off >= 1; off >>= 1) p += __shfl_xor(p, off, 64);
    if ((tid & 63) == 0) red[tid >> 6] = p;
    __syncthreads();
    if (tid == 0) c0[c] = red[0] + red[1] + red[2] + red[3] + b2[c];
}

__global__ __launch_bounds__(256) void mel_gather(
    const float* __restrict__ mel_s, const float* __restrict__ c0,
    const int* __restrict__ cum, float* __restrict__ mel_out)
{
    __shared__ int sc[256];
    __shared__ float s0[80];
    const int b = blockIdx.y;
    const int t = blockIdx.x * 256 + threadIdx.x;
    sc[threadIdx.x] = cum[b * 256 + threadIdx.x];
    if (threadIdx.x < 80) s0[threadIdx.x] = c0[threadIdx.x];
    __syncthreads();
    const int total = sc[255];
    int lo = 0, hi = 256;
    while (lo < hi) {
        int mid = (lo + hi) >> 1;
        if (sc[mid] <= t) lo = mid + 1; else hi = mid;
    }
    int row = lo < 255 ? lo : 255;
    const bool valid = t < total;
    const float* src = mel_s + ((size_t)b * 256 + row) * 80;
    for (int cc = 0; cc < 80; cc++) {
        float v = valid ? src[cc] : s0[cc];
        mel_out[((size_t)b * 80 + cc) * T_ + t] = v;
    }
}

// ---------------------------------------------------------------------------
extern "C" void kernel_launch(void* const* d_in, const int* in_sizes, int n_in,
                              void* d_out, int out_size, void* d_ws, size_t ws_size,
                              hipStream_t stream)
{
    const int*   text_ids     = (const int*)d_in[0];
    const int*   text_lengths = (const int*)d_in[1];
    const float* emb   = (const float*)d_in[3];
    const float* pe    = (const float*)d_in[4];
    const float* Wqkv  = (const float*)d_in[5];
    const float* bqkv  = (const float*)d_in[6];
    const float* Wo    = (const float*)d_in[7];
    const float* bo    = (const float*)d_in[8];
    const float* ln1_s = (const float*)d_in[9];
    const float* ln1_b = (const float*)d_in[10];
    const float* ln2_s = (const float*)d_in[11];
    const float* ln2_b = (const float*)d_in[12];
    const float* W1    = (const float*)d_in[13];
    const float* b1    = (const float*)d_in[14];
    const float* W2    = (const float*)d_in[15];
    const float* b2    = (const float*)d_in[16];
    const float* mel_W1 = (const float*)d_in[17];
    const float* mel_b1 = (const float*)d_in[18];
    const float* mel_W2 = (const float*)d_in[19];
    const float* mel_b2 = (const float*)d_in[20];
    const float* dur_W1 = (const float*)d_in[21];
    const float* dur_b1 = (const float*)d_in[22];
    const float* dur_W2 = (const float*)d_in[23];
    const float* dur_b2 = (const float*)d_in[24];

    float* out = (float*)d_out;
    float* mel_out = out;
    float* dur_out = out + (size_t)B_ * NM_ * T_;
    float* enc_out = dur_out + (size_t)B_ * S_;

    typedef unsigned short u16;
    char* w = (char*)d_ws;
    u16* Wqkv_t  = (u16*)w;                   w += (size_t)L_ * 1536 * 512 * 2;
    u16* Wo_t    = (u16*)w;                   w += (size_t)L_ * 512 * 512 * 2;
    u16* W1_t    = (u16*)w;                   w += (size_t)L_ * 2048 * 512 * 2;
    u16* W2_t    = (u16*)w;                   w += (size_t)L_ * 512 * 2048 * 2;
    u16* melW1_t = (u16*)w;                   w += (size_t)2048 * 512 * 2;
    u16* durW1_t = (u16*)w;                   w += (size_t)256 * 512 * 2;
    u16* x_bf    = (u16*)w;                   w += (size_t)M_ * 512 * 2;
    u16* qkv_bf  = (u16*)w;                   w += (size_t)M_ * 1536 * 2;
    u16* ao_bf   = (u16*)w;                   w += (size_t)M_ * 512 * 2;
    u16* y_bf    = (u16*)w;                   w += (size_t)M_ * 512 * 2;
    char* big    = w;                         w += (size_t)16777216;  // scores/ffh/melh/durh
    float* mel_s = (float*)w;                 w += (size_t)M_ * 80 * 4;
    float* c0    = (float*)w;                 w += 512;
    int*   cum   = (int*)w;                   w += (size_t)M_ * 4;

    u16* scores  = (u16*)big;
    u16* ffh     = (u16*)big;
    u16* melh    = (u16*)big;
    float* durh  = (float*)big;

    // weight conversion (transpose to [N][K] bf16)
    transpose_bf16<<<dim3(48, 16, 6), dim3(32, 8), 0, stream>>>(Wqkv, Wqkv_t, 512, 1536);
    transpose_bf16<<<dim3(16, 16, 6), dim3(32, 8), 0, stream>>>(Wo, Wo_t, 512, 512);
    transpose_bf16<<<dim3(64, 16, 6), dim3(32, 8), 0, stream>>>(W1, W1_t, 512, 2048);
    transpose_bf16<<<dim3(16, 64, 6), dim3(32, 8), 0, stream>>>(W2, W2_t, 2048, 512);
    transpose_bf16<<<dim3(64, 16, 1), dim3(32, 8), 0, stream>>>(mel_W1, melW1_t, 512, 2048);
    transpose_bf16<<<dim3(8, 16, 1), dim3(32, 8), 0, stream>>>(dur_W1, durW1_t, 512, 256);

    embed_bf16<<<M_, 128, 0, stream>>>(text_ids, emb, pe, x_bf);

    for (int l = 0; l < L_; l++) {
        gemm_bf16<<<dim3(12, 32), 256, 0, stream>>>(
            x_bf, Wqkv_t + (size_t)l * 1536 * 512, bqkv + (size_t)l * 1536,
            nullptr, qkv_bf, 1536, 512, 0, 0, 1);
        attn_scores_bf16<<<dim3(4, 4, 128), 256, 0, stream>>>(qkv_bf, text_lengths, scores);
        softmax_bf16<<<(B_ * H_ * S_) / 4, 256, 0, stream>>>(scores);
        attn_av_bf16<<<dim3(1, 8, 128), 256, 0, stream>>>(scores, qkv_bf, ao_bf);
        gemm_bf16<<<dim3(4, 32), 256, 0, stream>>>(
            ao_bf, Wo_t + (size_t)l * 512 * 512, bo + (size_t)l * 512,
            nullptr, y_bf, 512, 512, 0, 0, 1);
        add_ln_bf16<<<M_, 128, 0, stream>>>(
            x_bf, y_bf, ln1_s + (size_t)l * D_, ln1_b + (size_t)l * D_, nullptr);
        gemm_bf16<<<dim3(16, 32), 256, 0, stream>>>(
            x_bf, W1_t + (size_t)l * 2048 * 512, b1 + (size_t)l * 2048,
            nullptr, ffh, 2048, 512, 1, 0, 1);
        gemm_bf16<<<dim3(4, 32), 256, 0, stream>>>(
            ffh, W2_t + (size_t)l * 512 * 2048, b2 + (size_t)l * 512,
            nullptr, y_bf, 512, 2048, 0, 0, 1);
        add_ln_bf16<<<M_, 128, 0, stream>>>(
            x_bf, y_bf, ln2_s + (size_t)l * D_, ln2_b + (size_t)l * D_,
            (l == L_ - 1) ? enc_out : nullptr);
    }

    // duration head
    gemm_bf16<<<dim3(2, 32), 256, 0, stream>>>(
        x_bf, durW1_t, dur_b1, durh, nullptr, 256, 512, 1, 1, 0);
    dur_head2<<<M_ / 4, 256, 0, stream>>>(durh, dur_W2, dur_b2, dur_out);
    dur_cumsum<<<B_, 256, 0, stream>>>(dur_out, cum);

    // mel head on enc rows, then gather
    gemm_bf16<<<dim3(16, 32), 256, 0, stream>>>(
        x_bf, melW1_t, mel_b1, nullptr, melh, 2048, 512, 1, 0, 1);
    mel_out_gemm<<<M_ / 4, 320, 0, stream>>>(melh, mel_W2, mel_b2, mel_s);
    mel_c0<<<NM_, 256, 0, stream>>>(mel_b1, mel_W2, mel_b2, c0);
    mel_gather<<<dim3(T_ / 256, B_), 256, 0, stream>>>(mel_s, c0, cum, mel_out);
}

// Round 3
// 1168.319 us; speedup vs baseline: 3.4013x; 1.1992x over previous
//
#include <hip/hip_runtime.h>
#include <math.h>

#define B_ 16
#define S_ 256
#define T_ 2048
#define D_ 512
#define H_ 8
#define L_ 6
#define FF_ 2048
#define NM_ 80
#define M_ 4096  // B_*S_

typedef float floatx4 __attribute__((ext_vector_type(4)));
typedef __bf16 bf16x8 __attribute__((ext_vector_type(8)));

__device__ __forceinline__ float bf2f(unsigned u) {
    return __uint_as_float((u & 0xffffu) << 16);
}
__device__ __forceinline__ unsigned short f2bf(float f) {
    unsigned u = __float_as_uint(f);
    unsigned r = u + 0x7fffu + ((u >> 16) & 1u);
    return (unsigned short)(r >> 16);
}
__device__ __forceinline__ void gload_lds16(const void* g, void* l) {
    __builtin_amdgcn_global_load_lds(
        (const __attribute__((address_space(1))) void*)g,
        (__attribute__((address_space(3))) void*)l, 16, 0, 0);
}

// ---------------------------------------------------------------------------
// Tiled transpose + f32->bf16: src [Z][K][N] -> dst [Z][N][K] (bf16)
// ---------------------------------------------------------------------------
__global__ __launch_bounds__(256) void transpose_bf16(
    const float* __restrict__ src, unsigned short* __restrict__ dst,
    int K, int N)
{
    __shared__ float tile[32][33];
    const int k0 = blockIdx.y * 32, n0 = blockIdx.x * 32;
    src += (size_t)blockIdx.z * K * N;
    dst += (size_t)blockIdx.z * K * N;
    const int tx = threadIdx.x, ty = threadIdx.y;
#pragma unroll
    for (int i = 0; i < 32; i += 8)
        tile[ty + i][tx] = src[(size_t)(k0 + ty + i) * N + n0 + tx];
    __syncthreads();
#pragma unroll
    for (int i = 0; i < 32; i += 8)
        dst[(size_t)(n0 + ty + i) * K + k0 + tx] = f2bf(tile[tx][ty + i]);
}

// Transpose with column padding: src [K][Ns] f32 -> dst [Np][K] bf16, rows>=Ns zero
__global__ __launch_bounds__(256) void transpose_pad_bf16(
    const float* __restrict__ src, unsigned short* __restrict__ dst,
    int K, int Ns)
{
    __shared__ float tile[32][33];
    const int k0 = blockIdx.y * 32, n0 = blockIdx.x * 32;
    const int tx = threadIdx.x, ty = threadIdx.y;
#pragma unroll
    for (int i = 0; i < 32; i += 8) {
        int n = n0 + tx;
        tile[ty + i][tx] = (n < Ns) ? src[(size_t)(k0 + ty + i) * Ns + n] : 0.f;
    }
    __syncthreads();
#pragma unroll
    for (int i = 0; i < 32; i += 8)
        dst[(size_t)(n0 + ty + i) * K + k0 + tx] = f2bf(tile[tx][ty + i]);
}

__global__ __launch_bounds__(128) void pad_bias128(
    const float* __restrict__ src, float* __restrict__ dst, int n)
{
    int t = threadIdx.x;
    dst[t] = (t < n) ? src[t] : 0.f;
}

// ---------------------------------------------------------------------------
// Embedding + positional encoding -> bf16 x
// ---------------------------------------------------------------------------
__global__ __launch_bounds__(128) void embed_bf16(
    const int* __restrict__ ids, const float* __restrict__ emb,
    const float* __restrict__ pe, unsigned short* __restrict__ x)
{
    const int r = blockIdx.x;
    const int c = threadIdx.x * 4;
    const int id = ids[r];
    const int s = r & (S_ - 1);
    float4 e = *(const float4*)(emb + (size_t)id * D_ + c);
    float4 p = *(const float4*)(pe + (size_t)s * D_ + c);
    ushort4 o;
    o.x = f2bf(e.x + p.x); o.y = f2bf(e.y + p.y);
    o.z = f2bf(e.z + p.z); o.w = f2bf(e.w + p.w);
    *(ushort4*)(x + (size_t)r * D_ + c) = o;
}

// ---------------------------------------------------------------------------
// bf16 MFMA GEMM: C = act(A[M,K](bf16) @ Bt[N,K]^T(bf16) + bias[N](f32))
// ---------------------------------------------------------------------------
__global__ __launch_bounds__(256) void gemm_bf16(
    const unsigned short* __restrict__ A, const unsigned short* __restrict__ Bt,
    const float* __restrict__ bias, float* __restrict__ Cf,
    unsigned short* __restrict__ Cb, int N, int K, int act, int wf, int wb)
{
    __shared__ __attribute__((aligned(16))) char smem[32768];
    char* sA = smem;
    char* sB = smem + 16384;

    const int tid = threadIdx.x;
    const int wave = tid >> 6, lane = tid & 63;
    const int lm = lane & 15, quad = lane >> 4;
    const int wm = wave >> 1, wn = wave & 1;
    const int m0 = blockIdx.y * 128;
    const int n0 = blockIdx.x * 128;

    floatx4 acc[4][4];
#pragma unroll
    for (int i = 0; i < 4; i++)
#pragma unroll
        for (int j = 0; j < 4; j++) acc[i][j] = (floatx4){0.f, 0.f, 0.f, 0.f};

    const unsigned short* ga[8];
    char* lds[8];
#pragma unroll
    for (int j = 0; j < 8; j++) {
        int sid = wave * 8 + j;
        if (sid < 16) {
            int mi = sid >> 1, ki = sid & 1;
            ga[j] = A + (size_t)(m0 + mi * 16 + lm) * K + ki * 32 + quad * 8;
            lds[j] = sA + sid * 1024;
        } else {
            int t = sid - 16;
            int ni = t >> 1, ki = t & 1;
            ga[j] = Bt + (size_t)(n0 + ni * 16 + lm) * K + ki * 32 + quad * 8;
            lds[j] = sB + t * 1024;
        }
    }

    for (int kt = 0; kt < K; kt += 64) {
        __syncthreads();
#pragma unroll
        for (int j = 0; j < 8; j++) gload_lds16(ga[j] + kt, lds[j]);
        __syncthreads();
#pragma unroll
        for (int ki = 0; ki < 2; ki++) {
            bf16x8 af[4], bf[4];
#pragma unroll
            for (int i = 0; i < 4; i++) {
                af[i] = *(const bf16x8*)(sA + ((((wm * 4 + i) * 2 + ki) << 10) + (lane << 4)));
                bf[i] = *(const bf16x8*)(sB + ((((wn * 4 + i) * 2 + ki) << 10) + (lane << 4)));
            }
#pragma unroll
            for (int i = 0; i < 4; i++)
#pragma unroll
                for (int j = 0; j < 4; j++)
                    acc[i][j] = __builtin_amdgcn_mfma_f32_16x16x32_bf16(
                        af[i], bf[j], acc[i][j], 0, 0, 0);
        }
    }

#pragma unroll
    for (int mi = 0; mi < 4; mi++) {
        const int rb = m0 + wm * 64 + mi * 16 + quad * 4;
#pragma unroll
        for (int ni = 0; ni < 4; ni++) {
            const int col = n0 + wn * 64 + ni * 16 + lm;
            const float bv = bias[col];
#pragma unroll
            for (int r = 0; r < 4; r++) {
                float o = acc[mi][ni][r] + bv;
                if (act) o = fmaxf(o, 0.f);
                if (wf) Cf[(size_t)(rb + r) * N + col] = o;
                if (wb) Cb[(size_t)(rb + r) * N + col] = f2bf(o);
            }
        }
    }
}

// ---------------------------------------------------------------------------
// Transpose V slice of qkv into vt[(b*8+h)*64 + d][s]  (bf16)
// grid (4 s-tiles, 128 bh), block 256
// ---------------------------------------------------------------------------
__global__ __launch_bounds__(256) void transpose_v(
    const unsigned short* __restrict__ qkv, unsigned short* __restrict__ vt)
{
    __shared__ unsigned short tile[64][74];
    const int tid = threadIdx.x;
    const int bh = blockIdx.y;
    const int b = bh >> 3, h = bh & 7;
    const int s0 = blockIdx.x * 64;
    const int ty = tid >> 3, tx = tid & 7;
#pragma unroll
    for (int i = 0; i < 64; i += 32) {
        uint4 v = *(const uint4*)(qkv + (size_t)(b * 256 + s0 + ty + i) * 1536
                                  + 1024 + h * 64 + tx * 8);
        unsigned short* dstp = &tile[ty + i][tx * 8];
        const unsigned short* sp = (const unsigned short*)&v;
#pragma unroll
        for (int j = 0; j < 8; j++) dstp[j] = sp[j];
    }
    __syncthreads();
#pragma unroll
    for (int i = 0; i < 64; i += 32) {
        int d = ty + i;
        unsigned short tmp[8];
#pragma unroll
        for (int j = 0; j < 8; j++) tmp[j] = tile[tx * 8 + j][d];
        *(uint4*)(vt + (size_t)(bh * 64 + d) * 256 + s0 + tx * 8) = *(uint4*)tmp;
    }
}

// ---------------------------------------------------------------------------
// Fused attention: per (q-tile 128, bh). S=QK^T (MFMA) -> in-register softmax
// -> P via LDS (two 128-col halves) -> O=PV (MFMA, V from vt) -> /l -> bf16.
// ---------------------------------------------------------------------------
__global__ __launch_bounds__(256) void attn_fused(
    const unsigned short* __restrict__ qkv, const unsigned short* __restrict__ vt,
    const int* __restrict__ lens, unsigned short* __restrict__ o)
{
    __shared__ __attribute__((aligned(16))) char smem[34816];  // max(32K sK, 128*136*2 sP)
    const int tid = threadIdx.x;
    const int wave = tid >> 6, lane = tid & 63;
    const int lm = lane & 15, quad = lane >> 4;
    const int qt = blockIdx.x;
    const int bh = blockIdx.y;
    const int b = bh >> 3, h = bh & 7;
    const int len = lens[b];
    const unsigned short* Qb = qkv + ((size_t)b * 256 + qt * 128) * 1536 + h * 64;
    const unsigned short* Kb = qkv + (size_t)b * 256 * 1536 + 512 + h * 64;
    const unsigned short* Vt = vt + (size_t)bh * 64 * 256;

    // stage K fragments (32 subtiles of 16 keys x 32 d), 8 per wave
#pragma unroll
    for (int j = 0; j < 8; j++) {
        int sid = wave * 8 + j;
        int nf = sid >> 1, kf = sid & 1;
        gload_lds16(Kb + (size_t)(nf * 16 + lm) * 1536 + kf * 32 + quad * 8,
                    smem + sid * 1024);
    }
    // Q fragments (this wave's 32 rows)
    bf16x8 aq[2][2];
#pragma unroll
    for (int mi = 0; mi < 2; mi++)
#pragma unroll
        for (int kf = 0; kf < 2; kf++)
            aq[mi][kf] = *(const bf16x8*)(Qb + (size_t)(wave * 32 + mi * 16 + lm) * 1536
                                          + kf * 32 + quad * 8);
    __syncthreads();

    floatx4 accS[2][16];
#pragma unroll
    for (int mi = 0; mi < 2; mi++)
#pragma unroll
        for (int nf = 0; nf < 16; nf++) accS[mi][nf] = (floatx4){0.f, 0.f, 0.f, 0.f};

#pragma unroll
    for (int nf = 0; nf < 16; nf++) {
        bf16x8 bk0 = *(const bf16x8*)(smem + (nf * 2 + 0) * 1024 + lane * 16);
        bf16x8 bk1 = *(const bf16x8*)(smem + (nf * 2 + 1) * 1024 + lane * 16);
        accS[0][nf] = __builtin_amdgcn_mfma_f32_16x16x32_bf16(aq[0][0], bk0, accS[0][nf], 0, 0, 0);
        accS[0][nf] = __builtin_amdgcn_mfma_f32_16x16x32_bf16(aq[0][1], bk1, accS[0][nf], 0, 0, 0);
        accS[1][nf] = __builtin_amdgcn_mfma_f32_16x16x32_bf16(aq[1][0], bk0, accS[1][nf], 0, 0, 0);
        accS[1][nf] = __builtin_amdgcn_mfma_f32_16x16x32_bf16(aq[1][1], bk1, accS[1][nf], 0, 0, 0);
    }

    // mask + scale + softmax (row = quad*4 + r; full row lives in this quad)
    float lrow[2][4];
    const float scale = 0.125f;
#pragma unroll
    for (int mi = 0; mi < 2; mi++)
#pragma unroll
        for (int r = 0; r < 4; r++) {
            float mx = -1e30f;
#pragma unroll
            for (int nf = 0; nf < 16; nf++) {
                float s = accS[mi][nf][r] * scale + ((nf * 16 + lm >= len) ? -1e9f : 0.f);
                accS[mi][nf][r] = s;
                mx = fmaxf(mx, s);
            }
#pragma unroll
            for (int off = 1; off < 16; off <<= 1) mx = fmaxf(mx, __shfl_xor(mx, off, 64));
            float sum = 0.f;
#pragma unroll
            for (int nf = 0; nf < 16; nf++) {
                float e = __expf(accS[mi][nf][r] - mx);
                accS[mi][nf][r] = e;
                sum += e;
            }
#pragma unroll
            for (int off = 1; off < 16; off <<= 1) sum += __shfl_xor(sum, off, 64);
            lrow[mi][r] = sum;
        }

    // PV in two key-halves: P half -> LDS (A layout), V frags from vt (global)
    floatx4 accO[2][4];
#pragma unroll
    for (int mi = 0; mi < 2; mi++)
#pragma unroll
        for (int nj = 0; nj < 4; nj++) accO[mi][nj] = (floatx4){0.f, 0.f, 0.f, 0.f};

    unsigned short* sP = (unsigned short*)smem;
    const int rbase = wave * 32;
#pragma unroll
    for (int half = 0; half < 2; half++) {
        __syncthreads();
#pragma unroll
        for (int mi = 0; mi < 2; mi++)
#pragma unroll
            for (int nf2 = 0; nf2 < 8; nf2++) {
                int nf = half * 8 + nf2;
                int row = rbase + mi * 16 + quad * 4;
                int col = nf2 * 16 + lm;
#pragma unroll
                for (int r = 0; r < 4; r++)
                    sP[(row + r) * 136 + col] = f2bf(accS[mi][nf][r]);
            }
        __syncthreads();
#pragma unroll
        for (int ks2 = 0; ks2 < 4; ks2++) {
            bf16x8 ap[2];
#pragma unroll
            for (int mi = 0; mi < 2; mi++)
                ap[mi] = *(const bf16x8*)(sP + (rbase + mi * 16 + lm) * 136
                                          + ks2 * 32 + quad * 8);
            int ks = half * 4 + ks2;
#pragma unroll
            for (int nj = 0; nj < 4; nj++) {
                bf16x8 bv = *(const bf16x8*)(Vt + (size_t)(nj * 16 + lm) * 256
                                             + ks * 32 + quad * 8);
                accO[0][nj] = __builtin_amdgcn_mfma_f32_16x16x32_bf16(ap[0], bv, accO[0][nj], 0, 0, 0);
                accO[1][nj] = __builtin_amdgcn_mfma_f32_16x16x32_bf16(ap[1], bv, accO[1][nj], 0, 0, 0);
            }
        }
    }

    // epilogue: normalize by 1/l, write bf16
#pragma unroll
    for (int mi = 0; mi < 2; mi++) {
        float inv[4];
#pragma unroll
        for (int r = 0; r < 4; r++) inv[r] = 1.f / lrow[mi][r];
        const int grow = b * 256 + qt * 128 + rbase + mi * 16 + quad * 4;
#pragma unroll
        for (int nj = 0; nj < 4; nj++) {
            const int gcol = h * 64 + nj * 16 + lm;
#pragma unroll
            for (int r = 0; r < 4; r++)
                o[(size_t)(grow + r) * 512 + gcol] = f2bf(accO[mi][nj][r] * inv[r]);
        }
    }
}

// ---------------------------------------------------------------------------
// x = LayerNorm(x + y) (bf16 in/out, fp32 math); optional fp32 enc out.
// ---------------------------------------------------------------------------
__global__ __launch_bounds__(128) void add_ln_bf16(
    unsigned short* __restrict__ x, const unsigned short* __restrict__ y,
    const float* __restrict__ s, const float* __restrict__ bb,
    float* __restrict__ enc_opt)
{
    __shared__ float red[2];
    const int row = blockIdx.x;
    const int tid = threadIdx.x;
    const int c = tid * 4;
    ushort4 xv = *(const ushort4*)(x + (size_t)row * D_ + c);
    ushort4 yv = *(const ushort4*)(y + (size_t)row * D_ + c);
    float h[4];
    h[0] = bf2f(xv.x) + bf2f(yv.x);
    h[1] = bf2f(xv.y) + bf2f(yv.y);
    h[2] = bf2f(xv.z) + bf2f(yv.z);
    h[3] = bf2f(xv.w) + bf2f(yv.w);

    float sum = h[0] + h[1] + h[2] + h[3];
#pragma unroll
    for (int off = 32; off >= 1; off >>= 1) sum += __shfl_xor(sum, off, 64);
    if ((tid & 63) == 0) red[tid >> 6] = sum;
    __syncthreads();
    float mean = (red[0] + red[1]) * (1.f / 512.f);
    __syncthreads();

    float d[4];
    d[0] = h[0] - mean; d[1] = h[1] - mean; d[2] = h[2] - mean; d[3] = h[3] - mean;
    float sq = d[0] * d[0] + d[1] * d[1] + d[2] * d[2] + d[3] * d[3];
#pragma unroll
    for (int off = 32; off >= 1; off >>= 1) sq += __shfl_xor(sq, off, 64);
    if ((tid & 63) == 0) red[tid >> 6] = sq;
    __syncthreads();
    float var = (red[0] + red[1]) * (1.f / 512.f);
    float rs = rsqrtf(var + 1e-5f);

    float4 sv = *(const float4*)(s + c);
    float4 bv = *(const float4*)(bb + c);
    float o[4];
    o[0] = d[0] * rs * sv.x + bv.x;
    o[1] = d[1] * rs * sv.y + bv.y;
    o[2] = d[2] * rs * sv.z + bv.z;
    o[3] = d[3] * rs * sv.w + bv.w;
    ushort4 ov;
    ov.x = f2bf(o[0]); ov.y = f2bf(o[1]); ov.z = f2bf(o[2]); ov.w = f2bf(o[3]);
    *(ushort4*)(x + (size_t)row * D_ + c) = ov;
    if (enc_opt) {
        float4 e; e.x = o[0]; e.y = o[1]; e.z = o[2]; e.w = o[3];
        *(float4*)(enc_opt + (size_t)row * D_ + c) = e;
    }
}

// ---------------------------------------------------------------------------
// Duration head stage 2 (durh fp32)
// ---------------------------------------------------------------------------
__global__ __launch_bounds__(256) void dur_head2(
    const float* __restrict__ durh, const float* __restrict__ w2,
    const float* __restrict__ b2, float* __restrict__ durout)
{
    const int tid = threadIdx.x;
    const int w = tid >> 6, lane = tid & 63;
    const int r = blockIdx.x * 4 + w;
    float4 h = *(const float4*)(durh + (size_t)r * 256 + lane * 4);
    float4 wv = *(const float4*)(w2 + lane * 4);
    float p = h.x * wv.x + h.y * wv.y + h.z * wv.z + h.w * wv.w;
#pragma unroll
    for (int off = 32; off >= 1; off >>= 1) p += __shfl_xor(p, off, 64);
    if (lane == 0) {
        float v = p + b2[0];
        durout[r] = (v > 20.f) ? v : log1pf(expf(v));
    }
}

__global__ __launch_bounds__(256) void dur_cumsum(
    const float* __restrict__ dur, int* __restrict__ cum)
{
    __shared__ int sc[256];
    const int b = blockIdx.x, s = threadIdx.x;
    int d = (int)rintf(dur[b * 256 + s]);
    if (d < 1) d = 1;
    sc[s] = d;
    __syncthreads();
    for (int off = 1; off < 256; off <<= 1) {
        int v = sc[s];
        int add = (s >= off) ? sc[s - off] : 0;
        __syncthreads();
        sc[s] = v + add;
        __syncthreads();
    }
    cum[b * 256 + s] = sc[s];
}

__global__ __launch_bounds__(256) void mel_c0(
    const float* __restrict__ b1, const float* __restrict__ W2,
    const float* __restrict__ b2, float* __restrict__ c0)
{
    __shared__ float red[4];
    const int c = blockIdx.x;
    const int tid = threadIdx.x;
    float p = 0.f;
    for (int f = tid; f < 2048; f += 256)
        p += fmaxf(b1[f], 0.f) * W2[(size_t)f * 80 + c];
#pragma unroll
    for (int off = 32; off >= 1; off >>= 1) p += __shfl_xor(p, off, 64);
    if ((tid & 63) == 0) red[tid >> 6] = p;
    __syncthreads();
    if (tid == 0) c0[c] = red[0] + red[1] + red[2] + red[3] + b2[c];
}

// mel_s is [4096][128] fp32 (padded); gather valid rows, c0 elsewhere
__global__ __launch_bounds__(256) void mel_gather(
    const float* __restrict__ mel_s, const float* __restrict__ c0,
    const int* __restrict__ cum, float* __restrict__ mel_out)
{
    __shared__ int sc[256];
    __shared__ float s0[80];
    const int b = blockIdx.y;
    const int t = blockIdx.x * 256 + threadIdx.x;
    sc[threadIdx.x] = cum[b * 256 + threadIdx.x];
    if (threadIdx.x < 80) s0[threadIdx.x] = c0[threadIdx.x];
    __syncthreads();
    const int total = sc[255];
    int lo = 0, hi = 256;
    while (lo < hi) {
        int mid = (lo + hi) >> 1;
        if (sc[mid] <= t) lo = mid + 1; else hi = mid;
    }
    int row = lo < 255 ? lo : 255;
    const bool valid = t < total;
    const float* src = mel_s + ((size_t)b * 256 + row) * 128;
    for (int cc = 0; cc < 80; cc++) {
        float v = valid ? src[cc] : s0[cc];
        mel_out[((size_t)b * 80 + cc) * T_ + t] = v;
    }
}

// ---------------------------------------------------------------------------
extern "C" void kernel_launch(void* const* d_in, const int* in_sizes, int n_in,
                              void* d_out, int out_size, void* d_ws, size_t ws_size,
                              hipStream_t stream)
{
    const int*   text_ids     = (const int*)d_in[0];
    const int*   text_lengths = (const int*)d_in[1];
    const float* emb   = (const float*)d_in[3];
    const float* pe    = (const float*)d_in[4];
    const float* Wqkv  = (const float*)d_in[5];
    const float* bqkv  = (const float*)d_in[6];
    const float* Wo    = (const float*)d_in[7];
    const float* bo    = (const float*)d_in[8];
    const float* ln1_s = (const float*)d_in[9];
    const float* ln1_b = (const float*)d_in[10];
    const float* ln2_s = (const float*)d_in[11];
    const float* ln2_b = (const float*)d_in[12];
    const float* W1    = (const float*)d_in[13];
    const float* b1    = (const float*)d_in[14];
    const float* W2    = (const float*)d_in[15];
    const float* b2    = (const float*)d_in[16];
    const float* mel_W1 = (const float*)d_in[17];
    const float* mel_b1 = (const float*)d_in[18];
    const float* mel_W2 = (const float*)d_in[19];
    const float* mel_b2 = (const float*)d_in[20];
    const float* dur_W1 = (const float*)d_in[21];
    const float* dur_b1 = (const float*)d_in[22];
    const float* dur_W2 = (const float*)d_in[23];
    const float* dur_b2 = (const float*)d_in[24];

    float* out = (float*)d_out;
    float* mel_out = out;
    float* dur_out = out + (size_t)B_ * NM_ * T_;
    float* enc_out = dur_out + (size_t)B_ * S_;

    typedef unsigned short u16;
    char* w = (char*)d_ws;
    u16* Wqkv_t  = (u16*)w;                   w += (size_t)L_ * 1536 * 512 * 2;
    u16* Wo_t    = (u16*)w;                   w += (size_t)L_ * 512 * 512 * 2;
    u16* W1_t    = (u16*)w;                   w += (size_t)L_ * 2048 * 512 * 2;
    u16* W2_t    = (u16*)w;                   w += (size_t)L_ * 512 * 2048 * 2;
    u16* melW1_t = (u16*)w;                   w += (size_t)2048 * 512 * 2;
    u16* melW2_t = (u16*)w;                   w += (size_t)128 * 2048 * 2;
    u16* durW1_t = (u16*)w;                   w += (size_t)256 * 512 * 2;
    float* melb2p = (float*)w;                w += 512;
    u16* x_bf    = (u16*)w;                   w += (size_t)M_ * 512 * 2;
    u16* qkv_bf  = (u16*)w;                   w += (size_t)M_ * 1536 * 2;
    u16* ao_bf   = (u16*)w;                   w += (size_t)M_ * 512 * 2;
    u16* y_bf    = (u16*)w;                   w += (size_t)M_ * 512 * 2;
    char* big    = w;                         w += (size_t)16777216;  // ffh/melh/durh
    float* mel_s = (float*)w;                 w += (size_t)M_ * 128 * 4;
    float* c0    = (float*)w;                 w += 512;
    int*   cum   = (int*)w;                   w += (size_t)M_ * 4;

    u16* ffh     = (u16*)big;
    u16* melh    = (u16*)big;
    float* durh  = (float*)big;
    u16* vt      = (u16*)(big + 12582912);   // 4MB tail of big; liveness-disjoint from ffh

    // weight conversion
    transpose_bf16<<<dim3(48, 16, 6), dim3(32, 8), 0, stream>>>(Wqkv, Wqkv_t, 512, 1536);
    transpose_bf16<<<dim3(16, 16, 6), dim3(32, 8), 0, stream>>>(Wo, Wo_t, 512, 512);
    transpose_bf16<<<dim3(64, 16, 6), dim3(32, 8), 0, stream>>>(W1, W1_t, 512, 2048);
    transpose_bf16<<<dim3(16, 64, 6), dim3(32, 8), 0, stream>>>(W2, W2_t, 2048, 512);
    transpose_bf16<<<dim3(64, 16, 1), dim3(32, 8), 0, stream>>>(mel_W1, melW1_t, 512, 2048);
    transpose_pad_bf16<<<dim3(4, 64), dim3(32, 8), 0, stream>>>(mel_W2, melW2_t, 2048, 80);
    transpose_bf16<<<dim3(8, 16, 1), dim3(32, 8), 0, stream>>>(dur_W1, durW1_t, 512, 256);
    pad_bias128<<<1, 128, 0, stream>>>(mel_b2, melb2p, 80);

    embed_bf16<<<M_, 128, 0, stream>>>(text_ids, emb, pe, x_bf);

    for (int l = 0; l < L_; l++) {
        gemm_bf16<<<dim3(12, 32), 256, 0, stream>>>(
            x_bf, Wqkv_t + (size_t)l * 1536 * 512, bqkv + (size_t)l * 1536,
            nullptr, qkv_bf, 1536, 512, 0, 0, 1);
        transpose_v<<<dim3(4, 128), 256, 0, stream>>>(qkv_bf, vt);
        attn_fused<<<dim3(2, 128), 256, 0, stream>>>(qkv_bf, vt, text_lengths, ao_bf);
        gemm_bf16<<<dim3(4, 32), 256, 0, stream>>>(
            ao_bf, Wo_t + (size_t)l * 512 * 512, bo + (size_t)l * 512,
            nullptr, y_bf, 512, 512, 0, 0, 1);
        add_ln_bf16<<<M_, 128, 0, stream>>>(
            x_bf, y_bf, ln1_s + (size_t)l * D_, ln1_b + (size_t)l * D_, nullptr);
        gemm_bf16<<<dim3(16, 32), 256, 0, stream>>>(
            x_bf, W1_t + (size_t)l * 2048 * 512, b1 + (size_t)l * 2048,
            nullptr, ffh, 2048, 512, 1, 0, 1);
        gemm_bf16<<<dim3(4, 32), 256, 0, stream>>>(
            ffh, W2_t + (size_t)l * 512 * 2048, b2 + (size_t)l * 512,
            nullptr, y_bf, 512, 2048, 0, 0, 1);
        add_ln_bf16<<<M_, 128, 0, stream>>>(
            x_bf, y_bf, ln2_s + (size_t)l * D_, ln2_b + (size_t)l * D_,
            (l == L_ - 1) ? enc_out : nullptr);
    }

    // duration head
    gemm_bf16<<<dim3(2, 32), 256, 0, stream>>>(
        x_bf, durW1_t, dur_b1, durh, nullptr, 256, 512, 1, 1, 0);
    dur_head2<<<M_ / 4, 256, 0, stream>>>(durh, dur_W2, dur_b2, dur_out);
    dur_cumsum<<<B_, 256, 0, stream>>>(dur_out, cum);

    // mel head on enc rows (MFMA, N padded to 128), then gather
    gemm_bf16<<<dim3(16, 32), 256, 0, stream>>>(
        x_bf, melW1_t, mel_b1, nullptr, melh, 2048, 512, 1, 0, 1);
    gemm_bf16<<<dim3(1, 32), 256, 0, stream>>>(
        melh, melW2_t, melb2p, mel_s, nullptr, 128, 2048, 0, 1, 0);
    mel_c0<<<NM_, 256, 0, stream>>>(mel_b1, mel_W2, mel_b2, c0);
    mel_gather<<<dim3(T_ / 256, B_), 256, 0, stream>>>(mel_s, c0, cum, mel_out);
}

// Round 4
// 919.789 us; speedup vs baseline: 4.3204x; 1.2702x over previous
//
#include <hip/hip_runtime.h>
#include <math.h>

#define B_ 16
#define S_ 256
#define T_ 2048
#define D_ 512
#define H_ 8
#define L_ 6
#define FF_ 2048
#define NM_ 80
#define M_ 4096  // B_*S_

typedef float floatx4 __attribute__((ext_vector_type(4)));
typedef __bf16 bf16x8 __attribute__((ext_vector_type(8)));

__device__ __forceinline__ float bf2f(unsigned u) {
    return __uint_as_float((u & 0xffffu) << 16);
}
__device__ __forceinline__ unsigned short f2bf(float f) {
    unsigned u = __float_as_uint(f);
    unsigned r = u + 0x7fffu + ((u >> 16) & 1u);
    return (unsigned short)(r >> 16);
}
__device__ __forceinline__ void gload_lds16(const void* g, void* l) {
    __builtin_amdgcn_global_load_lds(
        (const __attribute__((address_space(1))) void*)g,
        (__attribute__((address_space(3))) void*)l, 16, 0, 0);
}

// ---------------------------------------------------------------------------
// Tiled transpose + f32->bf16: src [Z][K][N] -> dst [Z][N][K] (bf16)
// ---------------------------------------------------------------------------
__global__ __launch_bounds__(256) void transpose_bf16(
    const float* __restrict__ src, unsigned short* __restrict__ dst,
    int K, int N)
{
    __shared__ float tile[32][33];
    const int k0 = blockIdx.y * 32, n0 = blockIdx.x * 32;
    src += (size_t)blockIdx.z * K * N;
    dst += (size_t)blockIdx.z * K * N;
    const int tx = threadIdx.x, ty = threadIdx.y;
#pragma unroll
    for (int i = 0; i < 32; i += 8)
        tile[ty + i][tx] = src[(size_t)(k0 + ty + i) * N + n0 + tx];
    __syncthreads();
#pragma unroll
    for (int i = 0; i < 32; i += 8)
        dst[(size_t)(n0 + ty + i) * K + k0 + tx] = f2bf(tile[tx][ty + i]);
}

// Transpose with column padding: src [K][Ns] f32 -> dst [Np][K] bf16, rows>=Ns zero
__global__ __launch_bounds__(256) void transpose_pad_bf16(
    const float* __restrict__ src, unsigned short* __restrict__ dst,
    int K, int Ns)
{
    __shared__ float tile[32][33];
    const int k0 = blockIdx.y * 32, n0 = blockIdx.x * 32;
    const int tx = threadIdx.x, ty = threadIdx.y;
#pragma unroll
    for (int i = 0; i < 32; i += 8) {
        int n = n0 + tx;
        tile[ty + i][tx] = (n < Ns) ? src[(size_t)(k0 + ty + i) * Ns + n] : 0.f;
    }
    __syncthreads();
#pragma unroll
    for (int i = 0; i < 32; i += 8)
        dst[(size_t)(n0 + ty + i) * K + k0 + tx] = f2bf(tile[tx][ty + i]);
}

// ---------------------------------------------------------------------------
// Embedding + positional encoding -> bf16 x
// ---------------------------------------------------------------------------
__global__ __launch_bounds__(128) void embed_bf16(
    const int* __restrict__ ids, const float* __restrict__ emb,
    const float* __restrict__ pe, unsigned short* __restrict__ x)
{
    const int r = blockIdx.x;
    const int c = threadIdx.x * 4;
    const int id = ids[r];
    const int s = r & (S_ - 1);
    float4 e = *(const float4*)(emb + (size_t)id * D_ + c);
    float4 p = *(const float4*)(pe + (size_t)s * D_ + c);
    ushort4 o;
    o.x = f2bf(e.x + p.x); o.y = f2bf(e.y + p.y);
    o.z = f2bf(e.z + p.z); o.w = f2bf(e.w + p.w);
    *(ushort4*)(x + (size_t)r * D_ + c) = o;
}

// ---------------------------------------------------------------------------
// bf16 MFMA GEMM v2: double-buffered LDS, raw s_barrier + per-wave vmcnt.
// BM=128, BN in {128,64}, BK=64. Split-K via gridDim.z (partial fp32 out).
// Non-split: Cb = bf16 out with bias(+relu).  A [M,Kfull], Bt [N,Kfull].
// Kfull = klen * gridDim.z.
// ---------------------------------------------------------------------------
template<int BN>
__global__ __launch_bounds__(256) void gemm2(
    const unsigned short* __restrict__ A, const unsigned short* __restrict__ Bt,
    const float* __restrict__ bias, unsigned short* __restrict__ Cb,
    float* __restrict__ Cpart, int N, int klen, int act)
{
    constexpr int NSUB_B = BN / 8;          // B subtiles (16 or 8)
    constexpr int NSUB = 16 + NSUB_B;       // total subtiles per buffer
    constexpr int NL = NSUB / 4;            // loads per wave per buffer (8 or 6)
    constexpr int BUFSZ = NSUB * 1024;
    constexpr int WN = BN / 32;             // n-frags per wave (4 or 2)
    __shared__ __attribute__((aligned(16))) char smem[2 * BUFSZ];

    const int tid = threadIdx.x;
    const int wave = tid >> 6, lane = tid & 63;
    const int lm = lane & 15, quad = lane >> 4;
    const int wm = wave >> 1, wn = wave & 1;
    const int m0 = blockIdx.y * 128;
    const int n0 = blockIdx.x * BN;
    const int Kfull = klen * gridDim.z;
    const int kb = blockIdx.z * klen;

    floatx4 acc[4][WN];
#pragma unroll
    for (int i = 0; i < 4; i++)
#pragma unroll
        for (int j = 0; j < WN; j++) acc[i][j] = (floatx4){0.f, 0.f, 0.f, 0.f};

    const unsigned short* ga[NL];
    int loff[NL];
#pragma unroll
    for (int j = 0; j < NL; j++) {
        int sid = wave * NL + j;
        if (sid < 16) {
            int mi = sid >> 1, ki = sid & 1;
            ga[j] = A + (size_t)(m0 + mi * 16 + lm) * Kfull + kb + ki * 32 + quad * 8;
            loff[j] = sid * 1024;
        } else {
            int t = sid - 16;
            int ni = t >> 1, ki = t & 1;
            ga[j] = Bt + (size_t)(n0 + ni * 16 + lm) * Kfull + kb + ki * 32 + quad * 8;
            loff[j] = 16384 + t * 1024;
        }
    }

    // prologue: fill buffer 0
#pragma unroll
    for (int j = 0; j < NL; j++) gload_lds16(ga[j], smem + loff[j]);

    for (int kt = 0; kt < klen; kt += 64) {
        char* sc = smem + ((kt >> 6) & 1) * BUFSZ;
        if (kt + 64 < klen) {
            char* sn = smem + (((kt >> 6) + 1) & 1) * BUFSZ;
#pragma unroll
            for (int j = 0; j < NL; j++) gload_lds16(ga[j] + kt + 64, sn + loff[j]);
            __builtin_amdgcn_s_waitcnt(0x0F70 | NL);   // wait own current-buffer loads
        } else {
            __builtin_amdgcn_s_waitcnt(0x0F70);        // drain
        }
        asm volatile("" ::: "memory");
        __builtin_amdgcn_s_barrier();
        asm volatile("" ::: "memory");

#pragma unroll
        for (int ki = 0; ki < 2; ki++) {
            bf16x8 af[4], bfr[WN];
#pragma unroll
            for (int i = 0; i < 4; i++)
                af[i] = *(const bf16x8*)(sc + ((((wm * 4 + i) * 2 + ki) << 10) + (lane << 4)));
#pragma unroll
            for (int j = 0; j < WN; j++)
                bfr[j] = *(const bf16x8*)(sc + 16384 + ((((wn * WN + j) * 2 + ki) << 10) + (lane << 4)));
#pragma unroll
            for (int i = 0; i < 4; i++)
#pragma unroll
                for (int j = 0; j < WN; j++)
                    acc[i][j] = __builtin_amdgcn_mfma_f32_16x16x32_bf16(
                        af[i], bfr[j], acc[i][j], 0, 0, 0);
        }
        asm volatile("" ::: "memory");
        __builtin_amdgcn_s_barrier();   // all waves done reading sc before it is refilled
        asm volatile("" ::: "memory");
    }

    if (gridDim.z == 1) {
#pragma unroll
        for (int mi = 0; mi < 4; mi++) {
            const int rb = m0 + wm * 64 + mi * 16 + quad * 4;
#pragma unroll
            for (int nj = 0; nj < WN; nj++) {
                const int col = n0 + wn * (WN * 16) + nj * 16 + lm;
                const float bv = bias[col];
#pragma unroll
                for (int r = 0; r < 4; r++) {
                    float o = acc[mi][nj][r] + bv;
                    if (act) o = fmaxf(o, 0.f);
                    Cb[(size_t)(rb + r) * N + col] = f2bf(o);
                }
            }
        }
    } else {
        float* Cp = Cpart + (size_t)blockIdx.z * gridDim.y * 128 * N;
#pragma unroll
        for (int mi = 0; mi < 4; mi++) {
            const int rb = m0 + wm * 64 + mi * 16 + quad * 4;
#pragma unroll
            for (int nj = 0; nj < WN; nj++) {
                const int col = n0 + wn * (WN * 16) + nj * 16 + lm;
#pragma unroll
                for (int r = 0; r < 4; r++)
                    Cp[(size_t)(rb + r) * N + col] = acc[mi][nj][r];
            }
        }
    }
}

// ---------------------------------------------------------------------------
// Transpose V slice of qkv into vt[(b*8+h)*64 + d][s]  (bf16)
// ---------------------------------------------------------------------------
__global__ __launch_bounds__(256) void transpose_v(
    const unsigned short* __restrict__ qkv, unsigned short* __restrict__ vt)
{
    __shared__ unsigned short tile[64][74];
    const int tid = threadIdx.x;
    const int bh = blockIdx.y;
    const int b = bh >> 3, h = bh & 7;
    const int s0 = blockIdx.x * 64;
    const int ty = tid >> 3, tx = tid & 7;
#pragma unroll
    for (int i = 0; i < 64; i += 32) {
        uint4 v = *(const uint4*)(qkv + (size_t)(b * 256 + s0 + ty + i) * 1536
                                  + 1024 + h * 64 + tx * 8);
        unsigned short* dstp = &tile[ty + i][tx * 8];
        const unsigned short* sp = (const unsigned short*)&v;
#pragma unroll
        for (int j = 0; j < 8; j++) dstp[j] = sp[j];
    }
    __syncthreads();
#pragma unroll
    for (int i = 0; i < 64; i += 32) {
        int d = ty + i;
        unsigned short tmp[8];
#pragma unroll
        for (int j = 0; j < 8; j++) tmp[j] = tile[tx * 8 + j][d];
        *(uint4*)(vt + (size_t)(bh * 64 + d) * 256 + s0 + tx * 8) = *(uint4*)tmp;
    }
}

// ---------------------------------------------------------------------------
// Fused attention (as R3): S=QK^T (MFMA) -> in-register softmax -> P via LDS
// -> O=PV (MFMA, V from vt) -> /l -> bf16.
// ---------------------------------------------------------------------------
__global__ __launch_bounds__(256) void attn_fused(
    const unsigned short* __restrict__ qkv, const unsigned short* __restrict__ vt,
    const int* __restrict__ lens, unsigned short* __restrict__ o)
{
    __shared__ __attribute__((aligned(16))) char smem[34816];
    const int tid = threadIdx.x;
    const int wave = tid >> 6, lane = tid & 63;
    const int lm = lane & 15, quad = lane >> 4;
    const int qt = blockIdx.x;
    const int bh = blockIdx.y;
    const int b = bh >> 3, h = bh & 7;
    const int len = lens[b];
    const unsigned short* Qb = qkv + ((size_t)b * 256 + qt * 128) * 1536 + h * 64;
    const unsigned short* Kb = qkv + (size_t)b * 256 * 1536 + 512 + h * 64;
    const unsigned short* Vt = vt + (size_t)bh * 64 * 256;

#pragma unroll
    for (int j = 0; j < 8; j++) {
        int sid = wave * 8 + j;
        int nf = sid >> 1, kf = sid & 1;
        gload_lds16(Kb + (size_t)(nf * 16 + lm) * 1536 + kf * 32 + quad * 8,
                    smem + sid * 1024);
    }
    bf16x8 aq[2][2];
#pragma unroll
    for (int mi = 0; mi < 2; mi++)
#pragma unroll
        for (int kf = 0; kf < 2; kf++)
            aq[mi][kf] = *(const bf16x8*)(Qb + (size_t)(wave * 32 + mi * 16 + lm) * 1536
                                          + kf * 32 + quad * 8);
    __syncthreads();

    floatx4 accS[2][16];
#pragma unroll
    for (int mi = 0; mi < 2; mi++)
#pragma unroll
        for (int nf = 0; nf < 16; nf++) accS[mi][nf] = (floatx4){0.f, 0.f, 0.f, 0.f};

#pragma unroll
    for (int nf = 0; nf < 16; nf++) {
        bf16x8 bk0 = *(const bf16x8*)(smem + (nf * 2 + 0) * 1024 + lane * 16);
        bf16x8 bk1 = *(const bf16x8*)(smem + (nf * 2 + 1) * 1024 + lane * 16);
        accS[0][nf] = __builtin_amdgcn_mfma_f32_16x16x32_bf16(aq[0][0], bk0, accS[0][nf], 0, 0, 0);
        accS[0][nf] = __builtin_amdgcn_mfma_f32_16x16x32_bf16(aq[0][1], bk1, accS[0][nf], 0, 0, 0);
        accS[1][nf] = __builtin_amdgcn_mfma_f32_16x16x32_bf16(aq[1][0], bk0, accS[1][nf], 0, 0, 0);
        accS[1][nf] = __builtin_amdgcn_mfma_f32_16x16x32_bf16(aq[1][1], bk1, accS[1][nf], 0, 0, 0);
    }

    float lrow[2][4];
    const float scale = 0.125f;
#pragma unroll
    for (int mi = 0; mi < 2; mi++)
#pragma unroll
        for (int r = 0; r < 4; r++) {
            float mx = -1e30f;
#pragma unroll
            for (int nf = 0; nf < 16; nf++) {
                float s = accS[mi][nf][r] * scale + ((nf * 16 + lm >= len) ? -1e9f : 0.f);
                accS[mi][nf][r] = s;
                mx = fmaxf(mx, s);
            }
#pragma unroll
            for (int off = 1; off < 16; off <<= 1) mx = fmaxf(mx, __shfl_xor(mx, off, 64));
            float sum = 0.f;
#pragma unroll
            for (int nf = 0; nf < 16; nf++) {
                float e = __expf(accS[mi][nf][r] - mx);
                accS[mi][nf][r] = e;
                sum += e;
            }
#pragma unroll
            for (int off = 1; off < 16; off <<= 1) sum += __shfl_xor(sum, off, 64);
            lrow[mi][r] = sum;
        }

    floatx4 accO[2][4];
#pragma unroll
    for (int mi = 0; mi < 2; mi++)
#pragma unroll
        for (int nj = 0; nj < 4; nj++) accO[mi][nj] = (floatx4){0.f, 0.f, 0.f, 0.f};

    unsigned short* sP = (unsigned short*)smem;
    const int rbase = wave * 32;
#pragma unroll
    for (int half = 0; half < 2; half++) {
        __syncthreads();
#pragma unroll
        for (int mi = 0; mi < 2; mi++)
#pragma unroll
            for (int nf2 = 0; nf2 < 8; nf2++) {
                int nf = half * 8 + nf2;
                int row = rbase + mi * 16 + quad * 4;
                int col = nf2 * 16 + lm;
#pragma unroll
                for (int r = 0; r < 4; r++)
                    sP[(row + r) * 136 + col] = f2bf(accS[mi][nf][r]);
            }
        __syncthreads();
#pragma unroll
        for (int ks2 = 0; ks2 < 4; ks2++) {
            bf16x8 ap[2];
#pragma unroll
            for (int mi = 0; mi < 2; mi++)
                ap[mi] = *(const bf16x8*)(sP + (rbase + mi * 16 + lm) * 136
                                          + ks2 * 32 + quad * 8);
            int ks = half * 4 + ks2;
#pragma unroll
            for (int nj = 0; nj < 4; nj++) {
                bf16x8 bv = *(const bf16x8*)(Vt + (size_t)(nj * 16 + lm) * 256
                                             + ks * 32 + quad * 8);
                accO[0][nj] = __builtin_amdgcn_mfma_f32_16x16x32_bf16(ap[0], bv, accO[0][nj], 0, 0, 0);
                accO[1][nj] = __builtin_amdgcn_mfma_f32_16x16x32_bf16(ap[1], bv, accO[1][nj], 0, 0, 0);
            }
        }
    }

#pragma unroll
    for (int mi = 0; mi < 2; mi++) {
        float inv[4];
#pragma unroll
        for (int r = 0; r < 4; r++) inv[r] = 1.f / lrow[mi][r];
        const int grow = b * 256 + qt * 128 + rbase + mi * 16 + quad * 4;
#pragma unroll
        for (int nj = 0; nj < 4; nj++) {
            const int gcol = h * 64 + nj * 16 + lm;
#pragma unroll
            for (int r = 0; r < 4; r++)
                o[(size_t)(grow + r) * 512 + gcol] = f2bf(accO[mi][nj][r] * inv[r]);
        }
    }
}

// ---------------------------------------------------------------------------
// x = LayerNorm(x + y_bf16) (y already has bias)
// ---------------------------------------------------------------------------
__global__ __launch_bounds__(128) void add_ln_bf16(
    unsigned short* __restrict__ x, const unsigned short* __restrict__ y,
    const float* __restrict__ s, const float* __restrict__ bb)
{
    __shared__ float red[2];
    const int row = blockIdx.x;
    const int tid = threadIdx.x;
    const int c = tid * 4;
    ushort4 xv = *(const ushort4*)(x + (size_t)row * D_ + c);
    ushort4 yv = *(const ushort4*)(y + (size_t)row * D_ + c);
    float h[4];
    h[0] = bf2f(xv.x) + bf2f(yv.x);
    h[1] = bf2f(xv.y) + bf2f(yv.y);
    h[2] = bf2f(xv.z) + bf2f(yv.z);
    h[3] = bf2f(xv.w) + bf2f(yv.w);

    float sum = h[0] + h[1] + h[2] + h[3];
#pragma unroll
    for (int off = 32; off >= 1; off >>= 1) sum += __shfl_xor(sum, off, 64);
    if ((tid & 63) == 0) red[tid >> 6] = sum;
    __syncthreads();
    float mean = (red[0] + red[1]) * (1.f / 512.f);
    __syncthreads();

    float d[4];
    d[0] = h[0] - mean; d[1] = h[1] - mean; d[2] = h[2] - mean; d[3] = h[3] - mean;
    float sq = d[0] * d[0] + d[1] * d[1] + d[2] * d[2] + d[3] * d[3];
#pragma unroll
    for (int off = 32; off >= 1; off >>= 1) sq += __shfl_xor(sq, off, 64);
    if ((tid & 63) == 0) red[tid >> 6] = sq;
    __syncthreads();
    float var = (red[0] + red[1]) * (1.f / 512.f);
    float rs = rsqrtf(var + 1e-5f);

    float4 sv = *(const float4*)(s + c);
    float4 bv = *(const float4*)(bb + c);
    ushort4 ov;
    ov.x = f2bf(d[0] * rs * sv.x + bv.x);
    ov.y = f2bf(d[1] * rs * sv.y + bv.y);
    ov.z = f2bf(d[2] * rs * sv.z + bv.z);
    ov.w = f2bf(d[3] * rs * sv.w + bv.w);
    *(ushort4*)(x + (size_t)row * D_ + c) = ov;
}

// ---------------------------------------------------------------------------
// x = LayerNorm(x + p0 + p1 + bias) (split-K partials, fp32); optional enc out
// ---------------------------------------------------------------------------
__global__ __launch_bounds__(128) void add_ln_part(
    unsigned short* __restrict__ x, const float* __restrict__ p0,
    const float* __restrict__ p1, const float* __restrict__ bias,
    const float* __restrict__ s, const float* __restrict__ bb,
    float* __restrict__ enc_opt)
{
    __shared__ float red[2];
    const int row = blockIdx.x;
    const int tid = threadIdx.x;
    const int c = tid * 4;
    ushort4 xv = *(const ushort4*)(x + (size_t)row * D_ + c);
    float4 a = *(const float4*)(p0 + (size_t)row * D_ + c);
    float4 bq = *(const float4*)(p1 + (size_t)row * D_ + c);
    float4 bi = *(const float4*)(bias + c);
    float h[4];
    h[0] = bf2f(xv.x) + a.x + bq.x + bi.x;
    h[1] = bf2f(xv.y) + a.y + bq.y + bi.y;
    h[2] = bf2f(xv.z) + a.z + bq.z + bi.z;
    h[3] = bf2f(xv.w) + a.w + bq.w + bi.w;

    float sum = h[0] + h[1] + h[2] + h[3];
#pragma unroll
    for (int off = 32; off >= 1; off >>= 1) sum += __shfl_xor(sum, off, 64);
    if ((tid & 63) == 0) red[tid >> 6] = sum;
    __syncthreads();
    float mean = (red[0] + red[1]) * (1.f / 512.f);
    __syncthreads();

    float d[4];
    d[0] = h[0] - mean; d[1] = h[1] - mean; d[2] = h[2] - mean; d[3] = h[3] - mean;
    float sq = d[0] * d[0] + d[1] * d[1] + d[2] * d[2] + d[3] * d[3];
#pragma unroll
    for (int off = 32; off >= 1; off >>= 1) sq += __shfl_xor(sq, off, 64);
    if ((tid & 63) == 0) red[tid >> 6] = sq;
    __syncthreads();
    float var = (red[0] + red[1]) * (1.f / 512.f);
    float rs = rsqrtf(var + 1e-5f);

    float4 sv = *(const float4*)(s + c);
    float4 bv = *(const float4*)(bb + c);
    float o[4];
    o[0] = d[0] * rs * sv.x + bv.x;
    o[1] = d[1] * rs * sv.y + bv.y;
    o[2] = d[2] * rs * sv.z + bv.z;
    o[3] = d[3] * rs * sv.w + bv.w;
    ushort4 ov;
    ov.x = f2bf(o[0]); ov.y = f2bf(o[1]); ov.z = f2bf(o[2]); ov.w = f2bf(o[3]);
    *(ushort4*)(x + (size_t)row * D_ + c) = ov;
    if (enc_opt) {
        float4 e; e.x = o[0]; e.y = o[1]; e.z = o[2]; e.w = o[3];
        *(float4*)(enc_opt + (size_t)row * D_ + c) = e;
    }
}

// ---------------------------------------------------------------------------
// Duration head stage 2 from split-K partials: h = relu(p0+p1+b1), then
// softplus(h . w2 + b2).  One wave per row.
// ---------------------------------------------------------------------------
__global__ __launch_bounds__(256) void dur_head2(
    const float* __restrict__ p0, const float* __restrict__ p1,
    const float* __restrict__ b1, const float* __restrict__ w2,
    const float* __restrict__ b2, float* __restrict__ durout)
{
    const int tid = threadIdx.x;
    const int w = tid >> 6, lane = tid & 63;
    const int r = blockIdx.x * 4 + w;
    float4 a = *(const float4*)(p0 + (size_t)r * 256 + lane * 4);
    float4 bq = *(const float4*)(p1 + (size_t)r * 256 + lane * 4);
    float4 bi = *(const float4*)(b1 + lane * 4);
    float4 wv = *(const float4*)(w2 + lane * 4);
    float h0 = fmaxf(a.x + bq.x + bi.x, 0.f);
    float h1 = fmaxf(a.y + bq.y + bi.y, 0.f);
    float h2 = fmaxf(a.z + bq.z + bi.z, 0.f);
    float h3 = fmaxf(a.w + bq.w + bi.w, 0.f);
    float p = h0 * wv.x + h1 * wv.y + h2 * wv.z + h3 * wv.w;
#pragma unroll
    for (int off = 32; off >= 1; off >>= 1) p += __shfl_xor(p, off, 64);
    if (lane == 0) {
        float v = p + b2[0];
        durout[r] = (v > 20.f) ? v : log1pf(expf(v));
    }
}

__global__ __launch_bounds__(256) void dur_cumsum(
    const float* __restrict__ dur, int* __restrict__ cum)
{
    __shared__ int sc[256];
    const int b = blockIdx.x, s = threadIdx.x;
    int d = (int)rintf(dur[b * 256 + s]);
    if (d < 1) d = 1;
    sc[s] = d;
    __syncthreads();
    for (int off = 1; off < 256; off <<= 1) {
        int v = sc[s];
        int add = (s >= off) ? sc[s - off] : 0;
        __syncthreads();
        sc[s] = v + add;
        __syncthreads();
    }
    cum[b * 256 + s] = sc[s];
}

__global__ __launch_bounds__(256) void mel_c0(
    const float* __restrict__ b1, const float* __restrict__ W2,
    const float* __restrict__ b2, float* __restrict__ c0)
{
    __shared__ float red[4];
    const int c = blockIdx.x;
    const int tid = threadIdx.x;
    float p = 0.f;
    for (int f = tid; f < 2048; f += 256)
        p += fmaxf(b1[f], 0.f) * W2[(size_t)f * 80 + c];
#pragma unroll
    for (int off = 32; off >= 1; off >>= 1) p += __shfl_xor(p, off, 64);
    if ((tid & 63) == 0) red[tid >> 6] = p;
    __syncthreads();
    if (tid == 0) c0[c] = red[0] + red[1] + red[2] + red[3] + b2[c];
}

// mel partials: mp [4][4096][128] fp32; gather valid rows (sum 4 + bias), c0 else
__global__ __launch_bounds__(256) void mel_gather(
    const float* __restrict__ mp, const float* __restrict__ b2,
    const float* __restrict__ c0, const int* __restrict__ cum,
    float* __restrict__ mel_out)
{
    __shared__ int sc[256];
    __shared__ float s0[80];
    const int b = blockIdx.y;
    const int t = blockIdx.x * 256 + threadIdx.x;
    sc[threadIdx.x] = cum[b * 256 + threadIdx.x];
    if (threadIdx.x < 80) s0[threadIdx.x] = c0[threadIdx.x];
    __syncthreads();
    const int total = sc[255];
    int lo = 0, hi = 256;
    while (lo < hi) {
        int mid = (lo + hi) >> 1;
        if (sc[mid] <= t) lo = mid + 1; else hi = mid;
    }
    int row = lo < 255 ? lo : 255;
    const bool valid = t < total;
    const size_t base = ((size_t)b * 256 + row) * 128;
    const size_t plane = (size_t)M_ * 128;
    for (int cc = 0; cc < 80; cc++) {
        float v;
        if (valid)
            v = mp[base + cc] + mp[plane + base + cc] + mp[2 * plane + base + cc]
              + mp[3 * plane + base + cc] + b2[cc];
        else
            v = s0[cc];
        mel_out[((size_t)b * 80 + cc) * T_ + t] = v;
    }
}

// ---------------------------------------------------------------------------
extern "C" void kernel_launch(void* const* d_in, const int* in_sizes, int n_in,
                              void* d_out, int out_size, void* d_ws, size_t ws_size,
                              hipStream_t stream)
{
    const int*   text_ids     = (const int*)d_in[0];
    const int*   text_lengths = (const int*)d_in[1];
    const float* emb   = (const float*)d_in[3];
    const float* pe    = (const float*)d_in[4];
    const float* Wqkv  = (const float*)d_in[5];
    const float* bqkv  = (const float*)d_in[6];
    const float* Wo    = (const float*)d_in[7];
    const float* bo    = (const float*)d_in[8];
    const float* ln1_s = (const float*)d_in[9];
    const float* ln1_b = (const float*)d_in[10];
    const float* ln2_s = (const float*)d_in[11];
    const float* ln2_b = (const float*)d_in[12];
    const float* W1    = (const float*)d_in[13];
    const float* b1    = (const float*)d_in[14];
    const float* W2    = (const float*)d_in[15];
    const float* b2    = (const float*)d_in[16];
    const float* mel_W1 = (const float*)d_in[17];
    const float* mel_b1 = (const float*)d_in[18];
    const float* mel_W2 = (const float*)d_in[19];
    const float* mel_b2 = (const float*)d_in[20];
    const float* dur_W1 = (const float*)d_in[21];
    const float* dur_b1 = (const float*)d_in[22];
    const float* dur_W2 = (const float*)d_in[23];
    const float* dur_b2 = (const float*)d_in[24];

    float* out = (float*)d_out;
    float* mel_out = out;
    float* dur_out = out + (size_t)B_ * NM_ * T_;
    float* enc_out = dur_out + (size_t)B_ * S_;

    typedef unsigned short u16;
    char* w = (char*)d_ws;
    u16* Wqkv_t  = (u16*)w;                   w += (size_t)L_ * 1536 * 512 * 2;
    u16* Wo_t    = (u16*)w;                   w += (size_t)L_ * 512 * 512 * 2;
    u16* W1_t    = (u16*)w;                   w += (size_t)L_ * 2048 * 512 * 2;
    u16* W2_t    = (u16*)w;                   w += (size_t)L_ * 512 * 2048 * 2;
    u16* melW1_t = (u16*)w;                   w += (size_t)2048 * 512 * 2;
    u16* melW2_t = (u16*)w;                   w += (size_t)128 * 2048 * 2;
    u16* durW1_t = (u16*)w;                   w += (size_t)256 * 512 * 2;
    u16* x_bf    = (u16*)w;                   w += (size_t)M_ * 512 * 2;
    u16* qkv_bf  = (u16*)w;                   w += (size_t)M_ * 1536 * 2;  // \ contiguous:
    u16* ao_bf   = (u16*)w;                   w += (size_t)M_ * 512 * 2;   // / 16.78MB union
    u16* y_bf    = (u16*)w;                   w += (size_t)M_ * 512 * 2;
    char* big    = w;                         w += (size_t)16777216;       // ffh/melh (+vt tail)
    float* c0    = (float*)w;                 w += 512;
    int*   cum   = (int*)w;                   w += (size_t)M_ * 4;

    u16* ffh     = (u16*)big;
    u16* melh    = (u16*)big;
    u16* vt      = (u16*)(big + 12582912);    // 4MB tail; disjoint from ffh lifetime

    // split-K partials alias the (dead-at-use) qkv+ao region (16.78 MB fp32)
    float* part2 = (float*)qkv_bf;            // [2][4096][512] for FF2
    float* dpart = (float*)qkv_bf;            // [2][4096][256] for dur1
    float* mpart = (float*)(qkv_bf + (size_t)M_ * 512);  // [4][4096][128] for mel2

    // weight conversion
    transpose_bf16<<<dim3(48, 16, 6), dim3(32, 8), 0, stream>>>(Wqkv, Wqkv_t, 512, 1536);
    transpose_bf16<<<dim3(16, 16, 6), dim3(32, 8), 0, stream>>>(Wo, Wo_t, 512, 512);
    transpose_bf16<<<dim3(64, 16, 6), dim3(32, 8), 0, stream>>>(W1, W1_t, 512, 2048);
    transpose_bf16<<<dim3(16, 64, 6), dim3(32, 8), 0, stream>>>(W2, W2_t, 2048, 512);
    transpose_bf16<<<dim3(64, 16, 1), dim3(32, 8), 0, stream>>>(mel_W1, melW1_t, 512, 2048);
    transpose_pad_bf16<<<dim3(4, 64), dim3(32, 8), 0, stream>>>(mel_W2, melW2_t, 2048, 80);
    transpose_bf16<<<dim3(8, 16, 1), dim3(32, 8), 0, stream>>>(dur_W1, durW1_t, 512, 256);

    embed_bf16<<<M_, 128, 0, stream>>>(text_ids, emb, pe, x_bf);

    for (int l = 0; l < L_; l++) {
        gemm2<128><<<dim3(12, 32), 256, 0, stream>>>(
            x_bf, Wqkv_t + (size_t)l * 1536 * 512, bqkv + (size_t)l * 1536,
            qkv_bf, nullptr, 1536, 512, 0);
        transpose_v<<<dim3(4, 128), 256, 0, stream>>>(qkv_bf, vt);
        attn_fused<<<dim3(2, 128), 256, 0, stream>>>(qkv_bf, vt, text_lengths, ao_bf);
        gemm2<64><<<dim3(8, 32), 256, 0, stream>>>(
            ao_bf, Wo_t + (size_t)l * 512 * 512, bo + (size_t)l * 512,
            y_bf, nullptr, 512, 512, 0);
        add_ln_bf16<<<M_, 128, 0, stream>>>(
            x_bf, y_bf, ln1_s + (size_t)l * D_, ln1_b + (size_t)l * D_);
        gemm2<128><<<dim3(16, 32), 256, 0, stream>>>(
            x_bf, W1_t + (size_t)l * 2048 * 512, b1 + (size_t)l * 2048,
            ffh, nullptr, 2048, 512, 1);
        gemm2<64><<<dim3(8, 32, 2), 256, 0, stream>>>(
            ffh, W2_t + (size_t)l * 512 * 2048, nullptr,
            nullptr, part2, 512, 1024, 0);
        add_ln_part<<<M_, 128, 0, stream>>>(
            x_bf, part2, part2 + (size_t)M_ * 512, b2 + (size_t)l * 512,
            ln2_s + (size_t)l * D_, ln2_b + (size_t)l * D_,
            (l == L_ - 1) ? enc_out : nullptr);
    }

    // duration head (split-K=2 partials -> dur_head2 combines)
    gemm2<64><<<dim3(4, 32, 2), 256, 0, stream>>>(
        x_bf, durW1_t, nullptr, nullptr, dpart, 256, 256, 0);
    dur_head2<<<M_ / 4, 256, 0, stream>>>(
        dpart, dpart + (size_t)M_ * 256, dur_b1, dur_W2, dur_b2, dur_out);
    dur_cumsum<<<B_, 256, 0, stream>>>(dur_out, cum);

    // mel head: mel1 (bf16, relu), mel2 (split-K=4 partials -> gather combines)
    gemm2<128><<<dim3(16, 32), 256, 0, stream>>>(
        x_bf, melW1_t, mel_b1, melh, nullptr, 2048, 512, 1);
    gemm2<64><<<dim3(2, 32, 4), 256, 0, stream>>>(
        melh, melW2_t, nullptr, nullptr, mpart, 128, 512, 0);
    mel_c0<<<NM_, 256, 0, stream>>>(mel_b1, mel_W2, mel_b2, c0);
    mel_gather<<<dim3(T_ / 256, B_), 256, 0, stream>>>(mpart, mel_b2, c0, cum, mel_out);
}